// Round 16
// baseline (897.342 us; speedup 1.0000x reference)
//
#include <hip/hip_runtime.h>
#include <math.h>

#define NW   5
#define PRJ  14
#define CCH  512
#define PP   100
#define NQ   375
#define NS   70
#define NPAIR (NQ*NW)

// ws offsets (floats)
#define OFF_PROTO   0          // 256000
#define OFF_PAVG    256000     // 2560
#define OFF_QAVG    258560     // 192000
#define OFF_QSQ     450560     // 37500
#define OFF_PSQ     488060     // 500
#define OFF_LOGITS  488560     // 1875
#define OFF_PF16    490440     // 163840
#define OFF_AUX     654280     // 1875*204 = 382500
#define OFF_KG      1036780    // 18,750,000 dwords
#define OFF_QF16    19786844   // 375*16*2048 = 12,288,000 dwords
#define REQ2_WS_BYTES ((size_t)(OFF_QF16 + 12288000 + 64) * 4)

typedef float f32x16 __attribute__((ext_vector_type(16)));
typedef _Float16 f16x2 __attribute__((ext_vector_type(2)));
typedef _Float16 f16x8 __attribute__((ext_vector_type(8)));

__device__ __forceinline__ int SWZ(int n) { return n ^ ((n >> 2) & 7); }

// ---------------- K1: proto = mean over shots; proto_avg ----------------
__global__ void k_proto(const float* __restrict__ feat, float* __restrict__ ws) {
    int nc = blockIdx.x;
    int n  = nc >> 9;
    int p  = threadIdx.x;
    float s = 0.f;
    if (p < PP) {
        const float* base = feat + (size_t)((n * PRJ) * CCH) * PP + (size_t)(nc & 511) * PP + p;
        #pragma unroll
        for (int k = 0; k < PRJ; ++k) s += base[(size_t)k * CCH * PP];
        s *= (1.f / PRJ);
        ws[OFF_PROTO + nc * PP + p] = s;
    }
    float v = (p < PP) ? s : 0.f;
    #pragma unroll
    for (int off = 32; off; off >>= 1) v += __shfl_down(v, off);
    __shared__ float red[2];
    if ((threadIdx.x & 63) == 0) red[threadIdx.x >> 6] = v;
    __syncthreads();
    if (threadIdx.x == 0) ws[OFF_PAVG + nc] = (red[0] + red[1]) * (1.f / PP);
}

// ------- K2: per-image transpose-stats (+ optional fused f16-image emit)
__global__ __launch_bounds__(256) void k_qstat(const float* __restrict__ src,
                                               float* __restrict__ dst_sq,
                                               float* __restrict__ dst_avg,
                                               uint* __restrict__ qimg) {
    __shared__ __align__(16) float t[6400];
    int b = blockIdx.x, tid = threadIdx.x;
    const float* base = src + (size_t)b * CCH * PP;
    uint* imgb = qimg ? (qimg + (size_t)b * 32768) : (uint*)0;
    float qsq = 0.f;
    for (int c0 = 0; c0 < CCH; c0 += 64) {
        __syncthreads();
        const float4* g = (const float4*)(base + (size_t)c0 * PP);
        for (int i = tid; i < 1600; i += 256) ((float4*)t)[i] = g[i];
        __syncthreads();
        if (tid < PP) {
            #pragma unroll 8
            for (int c = 0; c < 64; ++c) { float x = t[c * PP + tid]; qsq = fmaf(x, x, qsq); }
        } else if (tid >= 128 && tid < 192) {
            int ch = tid - 128;
            const float4* row = (const float4*)(t + ch * PP);
            float s = 0.f;
            #pragma unroll
            for (int i = 0; i < 25; ++i) { float4 v = row[i]; s += (v.x + v.y) + (v.z + v.w); }
            if (dst_avg) dst_avg[(size_t)b * CCH + c0 + ch] = s * (1.f / PP);
        }
        if (imgb) {
            for (int i = tid; i < 3200; i += 256) {
                int cpl = i / 100, col = i - cpl * 100;
                int cp = (c0 >> 1) + cpl;
                int kt = cp >> 4, cpk = cp & 15;
                float a0 = t[(2 * cpl) * 100 + col];
                float a1 = t[(2 * cpl + 1) * 100 + col];
                uint pk = __builtin_bit_cast(uint, __builtin_amdgcn_cvt_pkrtz(a0, a1));
                imgb[(size_t)kt * 2048 + ((((cpk >> 2) << 7) | SWZ(col)) * 4 + (cpk & 3))] = pk;
            }
        }
    }
    if (tid < PP) dst_sq[b * PP + tid] = qsq;
}

// ------- K2c: fill avg row + pad slots of query images -------
__global__ __launch_bounds__(256) void k_qpad(const float* __restrict__ avg,
                                              uint* __restrict__ dst) {
    int b = blockIdx.x;
    int tid = threadIdx.x;
    uint* img = dst + (size_t)b * 32768;
    const float* av = avg + (size_t)b * CCH;
    if (tid < 256) {
        int kt = tid >> 4, cp = tid & 15;
        float a0 = av[kt * 32 + 2 * cp], a1 = av[kt * 32 + 2 * cp + 1];
        uint pk = __builtin_bit_cast(uint, __builtin_amdgcn_cvt_pkrtz(a0, a1));
        img[(size_t)kt * 2048 + (((cp >> 2) << 7) | 101) * 4 + (cp & 3)] = pk;
    }
    for (int i = tid; i < 6912; i += 256) {
        int dw = i & 3; int t2 = i >> 2;
        int k4 = t2 & 3; int t3 = t2 >> 2;
        int s_i = t3 % 27; int kt = t3 / 27;
        int s = 100 + s_i + (s_i >= 1 ? 1 : 0);   // skip slot 101
        uint val = (s == 100) ? 0x3C003C00u : 0u;
        img[(size_t)kt * 2048 + (((k4) << 7) | s) * 4 + dw] = val;
    }
}

// ------- K2b: convert f32 image -> SWZ'd f16 kt-images (protos) -------
__global__ __launch_bounds__(256) void k_conv(const float* __restrict__ src,
                                              const float* __restrict__ avg,
                                              uint* __restrict__ dst) {
    int b = blockIdx.x;          // id*16 + kt
    int id = b >> 4, kt = b & 15;
    int tid = threadIdx.x;
    int c0 = kt * 32;
    uint* img = dst + (size_t)b * 2048;
    const float* pb = src + (size_t)id * CCH * PP;
    const float* pavg = avg + (size_t)id * CCH;
    for (int i = tid; i < 1600; i += 256) {
        int cp = i / 100, col = i - cp * 100;
        float a0 = pb[(size_t)(c0 + 2 * cp) * PP + col];
        float a1 = pb[(size_t)(c0 + 2 * cp + 1) * PP + col];
        uint pk = __builtin_bit_cast(uint, __builtin_amdgcn_cvt_pkrtz(a0, a1));
        img[(((cp >> 2) << 7) | SWZ(col)) * 4 + (cp & 3)] = pk;
    }
    if (tid < 16) {
        int cp = tid;
        float a0 = pavg[c0 + 2 * cp], a1 = pavg[c0 + 2 * cp + 1];
        uint pk = __builtin_bit_cast(uint, __builtin_amdgcn_cvt_pkrtz(a0, a1));
        img[(((cp >> 2) << 7) | 101) * 4 + (cp & 3)] = pk;
    }
    for (int i = tid; i < 448; i += 256) {
        int dw = i & 3; int t2 = i >> 2;
        int s_i = t2 % 28; int k4 = t2 / 28;
        int s = 100 + s_i;
        if (s == 101) continue;
        img[(((k4) << 7) | s) * 4 + dw] = (s == 100) ? 0x3C003C00u : 0u;
    }
}

// ------- K3a-direct: MFMA operands straight from global images ----------
__global__ __launch_bounds__(256, 6) void k_cost2(float* __restrict__ ws) {
    __shared__ __align__(16) char SH[22400];
    __shared__ float wrL[PP], wcL[PP], qnl[PP], pnl[PP], sqv[PP], spv[PP];
    __shared__ float red[8];
    uint* Kst = (uint*)SH;

    int p_ = blockIdx.x;
    int xcd = p_ & 7, off_ = p_ >> 3;
    int pair = (xcd < 3) ? (xcd * 235 + off_) : (705 + (xcd - 3) * 234 + off_);

    int m = pair / NW;
    int n = pair - m * NW;
    int tid = threadIdx.x;
    int lane = tid & 63, wid = tid >> 6;
    int lrow = lane & 31, lhi = lane >> 5;

    const char* qimg = (const char*)((const uint*)(ws + OFF_QF16) + (size_t)m * 16 * 2048);
    const char* pimg = (const char*)((const uint*)(ws + OFF_PF16) + (size_t)n * 16 * 2048);

    f32x16 acc[4];
    #pragma unroll
    for (int tc = 0; tc < 4; ++tc)
        #pragma unroll
        for (int e = 0; e < 16; ++e) acc[tc][e] = 0.f;

    int arow16 = SWZ(32 * wid + lrow) * 16;
    int bcol16[4];
    #pragma unroll
    for (int tc = 0; tc < 4; ++tc) bcol16[tc] = SWZ(32 * tc + lrow) * 16;

    #pragma unroll 2
    for (int kt = 0; kt < 16; ++kt) {
        const char* qk = qimg + kt * 8192;
        const char* pk = pimg + kt * 8192;
        #pragma unroll
        for (int s = 0; s < 2; ++s) {
            int kb = (2 * s + lhi) * 2048;
            f16x8 ah = *(const f16x8*)(qk + kb + arow16);
            f16x8 b0 = *(const f16x8*)(pk + kb + bcol16[0]);
            f16x8 b1 = *(const f16x8*)(pk + kb + bcol16[1]);
            f16x8 b2 = *(const f16x8*)(pk + kb + bcol16[2]);
            f16x8 b3 = *(const f16x8*)(pk + kb + bcol16[3]);
            acc[0] = __builtin_amdgcn_mfma_f32_32x32x16_f16(ah, b0, acc[0], 0, 0, 0);
            acc[1] = __builtin_amdgcn_mfma_f32_32x32x16_f16(ah, b1, acc[1], 0, 0, 0);
            acc[2] = __builtin_amdgcn_mfma_f32_32x32x16_f16(ah, b2, acc[2], 0, 0, 0);
            acc[3] = __builtin_amdgcn_mfma_f32_32x32x16_f16(ah, b3, acc[3], 0, 0, 0);
        }
    }

    // extract w1 (col 100), sum_q (col 101), w2 (row 100), sum_p (row 101)
    if ((lane & 31) == 4 || (lane & 31) == 5) {
        float* dst = ((lane & 31) == 4) ? wrL : sqv;
        #pragma unroll
        for (int reg = 0; reg < 16; ++reg) {
            int row = 32 * wid + (reg & 3) + 8 * (reg >> 2) + 4 * lhi;
            if (row < PP) dst[row] = acc[3][reg];
        }
    }
    if (wid == 3 && lhi == 1) {
        #pragma unroll
        for (int tc = 0; tc < 4; ++tc) {
            int col = 32 * tc + lrow;
            if (col < PP) { wcL[col] = acc[tc][0]; spv[col] = acc[tc][1]; }
        }
    }
    __syncthreads();

    float v1 = 0.f, v2 = 0.f;
    if (tid < PP) {
        v1 = fmaxf(wrL[tid], 0.f) + 0.00101f;
        v2 = fmaxf(wcL[tid], 0.f) + 0.00101f;
    }
    float s1 = v1, s2 = v2;
    #pragma unroll
    for (int off = 32; off; off >>= 1) { s1 += __shfl_down(s1, off); s2 += __shfl_down(s2, off); }
    if ((tid & 63) == 0) { red[tid >> 6] = s1; red[4 + (tid >> 6)] = s2; }
    __syncthreads();
    float t1 = red[0] + red[1], t2 = red[4] + red[5];
    if (tid < PP) {
        wrL[tid] = v1 * (100.f / t1) * 4.f;
        wcL[tid] = v2 * (100.f / t2) * 4.f;
        float sq = sqv[tid], sp = spv[tid];
        qnl[tid] = ws[OFF_QSQ + m * PP + tid] - sq * sq * (1.f / 512.f);
        pnl[tid] = ws[OFF_PSQ + n * PP + tid] - sp * sp * (1.f / 512.f);
    }
    __syncthreads();

    float spc[4], pnc[4];
    #pragma unroll
    for (int tc = 0; tc < 4; ++tc) {
        int col = 32 * tc + lrow;
        bool cv = col < PP;
        spc[tc] = cv ? spv[col] : 0.f;
        pnc[tc] = cv ? pnl[col] : 0.f;
    }
    float mymax = -1e30f;
    #pragma unroll
    for (int reg = 0; reg < 16; ++reg) {
        int row = 32 * wid + (reg & 3) + 8 * (reg >> 2) + 4 * lhi;
        bool rv = row < PP;
        float sqr = rv ? sqv[row] : 0.f;
        float qnr = rv ? qnl[row] : 0.f;
        #pragma unroll
        for (int tc = 0; tc < 4; ++tc) {
            float sqd = qnr + pnc[tc] - 2.f * (acc[tc][reg] - sqr * spc[tc] * (1.f / 512.f));
            acc[tc][reg] = sqd;
            int col = 32 * tc + lrow;
            if (rv && col < PP) mymax = fmaxf(mymax, sqd);
        }
    }
    #pragma unroll
    for (int off = 32; off; off >>= 1) mymax = fmaxf(mymax, __shfl_down(mymax, off));
    __syncthreads();
    if (lane == 0) red[wid] = mymax;
    __syncthreads();
    float scale = fmaxf(fmaxf(red[0], red[1]), fmaxf(red[2], red[3])) + 1e-6f;
    float k2 = (1.f / scale) * (20.f * 1.44269504088896f);

    #pragma unroll
    for (int tc = 0; tc < 4; ++tc) {
        float kv[16];
        #pragma unroll
        for (int reg = 0; reg < 16; ++reg) kv[reg] = exp2f(fmaf(-acc[tc][reg], k2, 15.f));
        int col = 32 * tc + lrow;
        #pragma unroll
        for (int reg = 0; reg < 16; ++reg) {
            float pv = __shfl_xor(kv[reg], 1);
            int row = 32 * wid + (reg & 3) + 8 * (reg >> 2) + 4 * lhi;
            if (!(lane & 1) && row < PP && col < PP) {
                int j = col >> 1;
                int dw = (j < 25) ? j : (j + 3);
                uint pk = __builtin_bit_cast(uint, __builtin_amdgcn_cvt_pkrtz(kv[reg], pv));
                Kst[row * 56 + dw] = pk;
            }
        }
    }
    __syncthreads();

    // gather rows/cols; coalesced Kg layout: K[j][row] @0, KT[rp][col] @5000
    int r_ = tid >> 1, hf = tid & 1;
    bool sact = tid < 200;
    if (sact) {
        uint Kr[25], KTr[25];
        const uint* rp = Kst + r_ * 56 + 28 * hf;
        #pragma unroll
        for (int q = 0; q < 25; ++q) Kr[q] = rp[q];
        int j = r_ >> 1;
        int dwc = (j < 25) ? j : (j + 3);
        int sh = (r_ & 1) * 16;
        const uint* cp0 = Kst + (50 * hf) * 56 + dwc;
        #pragma unroll
        for (int q = 0; q < 25; ++q) {
            uint d0 = cp0[(2 * q) * 56];
            uint d1 = cp0[(2 * q + 1) * 56];
            KTr[q] = ((d0 >> sh) & 0xFFFFu) | (((d1 >> sh) & 0xFFFFu) << 16);
        }
        uint* kg = (uint*)(ws + OFF_KG) + (size_t)pair * 10000;
        #pragma unroll
        for (int q = 0; q < 25; ++q) kg[(25 * hf + q) * 100 + r_] = Kr[q];
        #pragma unroll
        for (int q = 0; q < 25; ++q) kg[5000 + (25 * hf + q) * 100 + r_] = KTr[q];
    }
    float* aux = ws + OFF_AUX + (size_t)pair * 204;
    if (tid < PP) { aux[tid] = wrL[tid]; aux[100 + tid] = wcL[tid]; }
    if (tid == 0) aux[200] = scale;
}

// ------- K3a-fallback: LDS-staging variant (same new Kg layout) -------
__global__ __launch_bounds__(256, 4) void k_costL(const float* __restrict__ query,
                                                  float* __restrict__ ws) {
    __shared__ __align__(16) char SH[22400];
    __shared__ float wrL[PP], wcL[PP], qnl[PP], pnl[PP], sqv[PP], spv[PP];
    __shared__ float red[8];
    uint* Kst = (uint*)SH;

    int p_ = blockIdx.x;
    int xcd = p_ & 7, off_ = p_ >> 3;
    int pair = (xcd < 3) ? (xcd * 235 + off_) : (705 + (xcd - 3) * 234 + off_);

    int m = pair / NW;
    int n = pair - m * NW;
    int tid = threadIdx.x;
    int lane = tid & 63, wid = tid >> 6;
    int lrow = lane & 31, lhi = lane >> 5;

    const float* qb = query + (size_t)m * CCH * PP;
    const float* qavg_g = ws + OFF_QAVG + (size_t)m * CCH;
    const uint* pimg = (const uint*)(ws + OFF_PF16) + (size_t)n * 16 * 2048;

    for (int idx = tid; idx < 112; idx += 256) {
        int s_i = idx % 28; int k4 = idx / 28;
        int s = 100 + s_i;
        if (s == 101) continue;
        uint4 val = (s == 100)
                  ? make_uint4(0x3C003C00u, 0x3C003C00u, 0x3C003C00u, 0x3C003C00u)
                  : make_uint4(0u, 0u, 0u, 0u);
        *(uint4*)&SH[(k4 * 128 + s) * 16] = val;
    }

    f32x16 acc[4];
    #pragma unroll
    for (int tc = 0; tc < 4; ++tc)
        #pragma unroll
        for (int e = 0; e < 16; ++e) acc[tc][e] = 0.f;

    int arow16 = SWZ(32 * wid + lrow) * 16;
    int bcol16[4];
    #pragma unroll
    for (int tc = 0; tc < 4; ++tc) bcol16[tc] = SWZ(32 * tc + lrow) * 16;

    for (int kt = 0; kt < 16; ++kt) {
        int c0 = kt * 32;
        for (int idx = tid; idx < 400; idx += 256) {
            int cp = idx / 25, n4 = idx - cp * 25;
            const float* src = qb + (size_t)(c0 + 2 * cp) * PP + n4 * 4;
            float4 x0 = *(const float4*)src;
            float4 x1 = *(const float4*)(src + PP);
            const float* p0 = (const float*)&x0;
            const float* p1 = (const float*)&x1;
            int basedw = ((cp >> 2) << 7);
            int dwb = (cp & 3) * 4;
            #pragma unroll
            for (int i4 = 0; i4 < 4; ++i4) {
                int node = n4 * 4 + i4;
                uint pk = __builtin_bit_cast(uint, __builtin_amdgcn_cvt_pkrtz(p0[i4], p1[i4]));
                *(uint*)&SH[(basedw + SWZ(node)) * 16 + dwb] = pk;
            }
        }
        if (tid < 16) {
            int cp = tid;
            uint pk = __builtin_bit_cast(uint,
                __builtin_amdgcn_cvt_pkrtz(qavg_g[c0 + 2 * cp], qavg_g[c0 + 2 * cp + 1]));
            *(uint*)&SH[(((cp >> 2) << 7) + 101) * 16 + (cp & 3) * 4] = pk;
        }
        {
            const float4* gB = (const float4*)(pimg + (size_t)kt * 2048);
            float4* sB = (float4*)&SH[8192];
            for (int i = tid; i < 512; i += 256) sB[i] = gB[i];
        }
        __syncthreads();
        __builtin_amdgcn_s_setprio(1);
        #pragma unroll
        for (int s = 0; s < 2; ++s) {
            int kb = (2 * s + lhi) * 2048;
            f16x8 ah = *(const f16x8*)&SH[kb + arow16];
            #pragma unroll
            for (int tc = 0; tc < 4; ++tc) {
                f16x8 bh = *(const f16x8*)&SH[8192 + kb + bcol16[tc]];
                acc[tc] = __builtin_amdgcn_mfma_f32_32x32x16_f16(ah, bh, acc[tc], 0, 0, 0);
            }
        }
        __builtin_amdgcn_s_setprio(0);
        __syncthreads();
    }

    if ((lane & 31) == 4 || (lane & 31) == 5) {
        float* dst = ((lane & 31) == 4) ? wrL : sqv;
        #pragma unroll
        for (int reg = 0; reg < 16; ++reg) {
            int row = 32 * wid + (reg & 3) + 8 * (reg >> 2) + 4 * lhi;
            if (row < PP) dst[row] = acc[3][reg];
        }
    }
    if (wid == 3 && lhi == 1) {
        #pragma unroll
        for (int tc = 0; tc < 4; ++tc) {
            int col = 32 * tc + lrow;
            if (col < PP) { wcL[col] = acc[tc][0]; spv[col] = acc[tc][1]; }
        }
    }
    __syncthreads();

    float v1 = 0.f, v2 = 0.f;
    if (tid < PP) {
        v1 = fmaxf(wrL[tid], 0.f) + 0.00101f;
        v2 = fmaxf(wcL[tid], 0.f) + 0.00101f;
    }
    float s1 = v1, s2 = v2;
    #pragma unroll
    for (int off = 32; off; off >>= 1) { s1 += __shfl_down(s1, off); s2 += __shfl_down(s2, off); }
    if ((tid & 63) == 0) { red[tid >> 6] = s1; red[4 + (tid >> 6)] = s2; }
    __syncthreads();
    float t1 = red[0] + red[1], t2 = red[4] + red[5];
    if (tid < PP) {
        wrL[tid] = v1 * (100.f / t1) * 4.f;
        wcL[tid] = v2 * (100.f / t2) * 4.f;
        float sq = sqv[tid], sp = spv[tid];
        qnl[tid] = ws[OFF_QSQ + m * PP + tid] - sq * sq * (1.f / 512.f);
        pnl[tid] = ws[OFF_PSQ + n * PP + tid] - sp * sp * (1.f / 512.f);
    }
    __syncthreads();

    float spc[4], pnc[4];
    #pragma unroll
    for (int tc = 0; tc < 4; ++tc) {
        int col = 32 * tc + lrow;
        bool cv = col < PP;
        spc[tc] = cv ? spv[col] : 0.f;
        pnc[tc] = cv ? pnl[col] : 0.f;
    }
    float mymax = -1e30f;
    #pragma unroll
    for (int reg = 0; reg < 16; ++reg) {
        int row = 32 * wid + (reg & 3) + 8 * (reg >> 2) + 4 * lhi;
        bool rv = row < PP;
        float sqr = rv ? sqv[row] : 0.f;
        float qnr = rv ? qnl[row] : 0.f;
        #pragma unroll
        for (int tc = 0; tc < 4; ++tc) {
            float sqd = qnr + pnc[tc] - 2.f * (acc[tc][reg] - sqr * spc[tc] * (1.f / 512.f));
            acc[tc][reg] = sqd;
            int col = 32 * tc + lrow;
            if (rv && col < PP) mymax = fmaxf(mymax, sqd);
        }
    }
    #pragma unroll
    for (int off = 32; off; off >>= 1) mymax = fmaxf(mymax, __shfl_down(mymax, off));
    __syncthreads();
    if (lane == 0) red[wid] = mymax;
    __syncthreads();
    float scale = fmaxf(fmaxf(red[0], red[1]), fmaxf(red[2], red[3])) + 1e-6f;
    float k2 = (1.f / scale) * (20.f * 1.44269504088896f);

    #pragma unroll
    for (int tc = 0; tc < 4; ++tc) {
        float kv[16];
        #pragma unroll
        for (int reg = 0; reg < 16; ++reg) kv[reg] = exp2f(fmaf(-acc[tc][reg], k2, 15.f));
        int col = 32 * tc + lrow;
        #pragma unroll
        for (int reg = 0; reg < 16; ++reg) {
            float pv = __shfl_xor(kv[reg], 1);
            int row = 32 * wid + (reg & 3) + 8 * (reg >> 2) + 4 * lhi;
            if (!(lane & 1) && row < PP && col < PP) {
                int j = col >> 1;
                int dw = (j < 25) ? j : (j + 3);
                uint pk = __builtin_bit_cast(uint, __builtin_amdgcn_cvt_pkrtz(kv[reg], pv));
                Kst[row * 56 + dw] = pk;
            }
        }
    }
    __syncthreads();

    int r_ = tid >> 1, hf = tid & 1;
    bool sact = tid < 200;
    if (sact) {
        uint Kr[25], KTr[25];
        const uint* rp = Kst + r_ * 56 + 28 * hf;
        #pragma unroll
        for (int q = 0; q < 25; ++q) Kr[q] = rp[q];
        int j = r_ >> 1;
        int dwc = (j < 25) ? j : (j + 3);
        int sh = (r_ & 1) * 16;
        const uint* cp0 = Kst + (50 * hf) * 56 + dwc;
        #pragma unroll
        for (int q = 0; q < 25; ++q) {
            uint d0 = cp0[(2 * q) * 56];
            uint d1 = cp0[(2 * q + 1) * 56];
            KTr[q] = ((d0 >> sh) & 0xFFFFu) | (((d1 >> sh) & 0xFFFFu) << 16);
        }
        uint* kg = (uint*)(ws + OFF_KG) + (size_t)pair * 10000;
        #pragma unroll
        for (int q = 0; q < 25; ++q) kg[(25 * hf + q) * 100 + r_] = Kr[q];
        #pragma unroll
        for (int q = 0; q < 25; ++q) kg[5000 + (25 * hf + q) * 100 + r_] = KTr[q];
    }
    float* aux = ws + OFF_AUX + (size_t)pair * 204;
    if (tid < PP) { aux[tid] = wrL[tid]; aux[100 + tid] = wcL[tid]; }
    if (tid == 0) aux[200] = scale;
}

// ------- K3b: k_sink — one wave per pair, register-resident K -------
__global__ __launch_bounds__(64, 2) void k_sink(float* __restrict__ ws) {
    __shared__ __align__(16) uint uhL[52], vhL[52];
    int pair = blockIdx.x;
    int l = threadIdx.x;
    bool act = l < 50;

    const float* aux = ws + OFF_AUX + (size_t)pair * 204;
    float wr0 = 0.f, wr1 = 0.f, wc0 = 0.f, wc1 = 0.f;
    if (act) {
        wr0 = aux[2 * l]; wr1 = aux[2 * l + 1];
        wc0 = aux[100 + 2 * l]; wc1 = aux[101 + 2 * l];
    }
    float scale = aux[200];
    float rk2 = scale * (1.f / (20.f * 1.44269504088896f));

    uint K0[50], K1[50], T0[50], T1[50];
    {
        const uint2* kg2 = (const uint2*)((const uint*)(ws + OFF_KG) + (size_t)pair * 10000);
        int ll = act ? l : 0;
        #pragma unroll
        for (int j = 0; j < 50; ++j) { uint2 kk = kg2[j * 50 + ll]; K0[j] = kk.x; K1[j] = kk.y; }
        #pragma unroll
        for (int j = 0; j < 50; ++j) { uint2 kk = kg2[2500 + j * 50 + ll]; T0[j] = kk.x; T1[j] = kk.y; }
    }
    if (l < 52) { vhL[l] = (l < 50) ? 0x3C003C00u : 0u; uhL[l] = 0u; }
    __syncthreads();

    float u0 = 0.f, u1 = 0.f;
    for (int it = 0; it < 50; ++it) {
        if (act) {
            const uint4* vp4 = (const uint4*)vhL;
            float a0 = 0.f, b0 = 0.f, a1 = 0.f, b1 = 0.f;
            #pragma unroll
            for (int d4 = 0; d4 < 12; ++d4) {
                uint4 V = vp4[d4];
                a0 = __builtin_amdgcn_fdot2(__builtin_bit_cast(f16x2, K0[4*d4+0]), __builtin_bit_cast(f16x2, V.x), a0, false);
                b0 = __builtin_amdgcn_fdot2(__builtin_bit_cast(f16x2, K0[4*d4+1]), __builtin_bit_cast(f16x2, V.y), b0, false);
                a0 = __builtin_amdgcn_fdot2(__builtin_bit_cast(f16x2, K0[4*d4+2]), __builtin_bit_cast(f16x2, V.z), a0, false);
                b0 = __builtin_amdgcn_fdot2(__builtin_bit_cast(f16x2, K0[4*d4+3]), __builtin_bit_cast(f16x2, V.w), b0, false);
                a1 = __builtin_amdgcn_fdot2(__builtin_bit_cast(f16x2, K1[4*d4+0]), __builtin_bit_cast(f16x2, V.x), a1, false);
                b1 = __builtin_amdgcn_fdot2(__builtin_bit_cast(f16x2, K1[4*d4+1]), __builtin_bit_cast(f16x2, V.y), b1, false);
                a1 = __builtin_amdgcn_fdot2(__builtin_bit_cast(f16x2, K1[4*d4+2]), __builtin_bit_cast(f16x2, V.z), a1, false);
                b1 = __builtin_amdgcn_fdot2(__builtin_bit_cast(f16x2, K1[4*d4+3]), __builtin_bit_cast(f16x2, V.w), b1, false);
            }
            {
                uint v48 = vhL[48], v49 = vhL[49];
                a0 = __builtin_amdgcn_fdot2(__builtin_bit_cast(f16x2, K0[48]), __builtin_bit_cast(f16x2, v48), a0, false);
                b0 = __builtin_amdgcn_fdot2(__builtin_bit_cast(f16x2, K0[49]), __builtin_bit_cast(f16x2, v49), b0, false);
                a1 = __builtin_amdgcn_fdot2(__builtin_bit_cast(f16x2, K1[48]), __builtin_bit_cast(f16x2, v48), a1, false);
                b1 = __builtin_amdgcn_fdot2(__builtin_bit_cast(f16x2, K1[49]), __builtin_bit_cast(f16x2, v49), b1, false);
            }
            u0 = fminf(wr0 * __builtin_amdgcn_rcpf(a0 + b0), 60000.f);
            u1 = fminf(wr1 * __builtin_amdgcn_rcpf(a1 + b1), 60000.f);
            uhL[l] = __builtin_bit_cast(uint, __builtin_amdgcn_cvt_pkrtz(u0, u1));
        }
        __syncthreads();
        if (act) {
            const uint4* up4 = (const uint4*)uhL;
            float a0 = 0.f, b0 = 0.f, a1 = 0.f, b1 = 0.f;
            #pragma unroll
            for (int d4 = 0; d4 < 12; ++d4) {
                uint4 U = up4[d4];
                a0 = __builtin_amdgcn_fdot2(__builtin_bit_cast(f16x2, T0[4*d4+0]), __builtin_bit_cast(f16x2, U.x), a0, false);
                b0 = __builtin_amdgcn_fdot2(__builtin_bit_cast(f16x2, T0[4*d4+1]), __builtin_bit_cast(f16x2, U.y), b0, false);
                a0 = __builtin_amdgcn_fdot2(__builtin_bit_cast(f16x2, T0[4*d4+2]), __builtin_bit_cast(f16x2, U.z), a0, false);
                b0 = __builtin_amdgcn_fdot2(__builtin_bit_cast(f16x2, T0[4*d4+3]), __builtin_bit_cast(f16x2, U.w), b0, false);
                a1 = __builtin_amdgcn_fdot2(__builtin_bit_cast(f16x2, T1[4*d4+0]), __builtin_bit_cast(f16x2, U.x), a1, false);
                b1 = __builtin_amdgcn_fdot2(__builtin_bit_cast(f16x2, T1[4*d4+1]), __builtin_bit_cast(f16x2, U.y), b1, false);
                a1 = __builtin_amdgcn_fdot2(__builtin_bit_cast(f16x2, T1[4*d4+2]), __builtin_bit_cast(f16x2, U.z), a1, false);
                b1 = __builtin_amdgcn_fdot2(__builtin_bit_cast(f16x2, T1[4*d4+3]), __builtin_bit_cast(f16x2, U.w), b1, false);
            }
            {
                uint u48 = uhL[48], u49 = uhL[49];
                a0 = __builtin_amdgcn_fdot2(__builtin_bit_cast(f16x2, T0[48]), __builtin_bit_cast(f16x2, u48), a0, false);
                b0 = __builtin_amdgcn_fdot2(__builtin_bit_cast(f16x2, T0[49]), __builtin_bit_cast(f16x2, u49), b0, false);
                a1 = __builtin_amdgcn_fdot2(__builtin_bit_cast(f16x2, T1[48]), __builtin_bit_cast(f16x2, u48), a1, false);
                b1 = __builtin_amdgcn_fdot2(__builtin_bit_cast(f16x2, T1[49]), __builtin_bit_cast(f16x2, u49), b1, false);
            }
            float v0 = fminf(wc0 * __builtin_amdgcn_rcpf(a0 + b0), 60000.f);
            float v1n = fminf(wc1 * __builtin_amdgcn_rcpf(a1 + b1), 60000.f);
            vhL[l] = __builtin_bit_cast(uint, __builtin_amdgcn_cvt_pkrtz(v0, v1n));
        }
        __syncthreads();
    }

    float lsum = 0.f;
    if (act) {
        float l0 = 0.f, l1 = 0.f;
        #pragma unroll
        for (int d = 0; d < 50; ++d) {
            f16x2 vv = __builtin_bit_cast(f16x2, vhL[d]);
            f16x2 h0 = __builtin_bit_cast(f16x2, K0[d]);
            f16x2 h1 = __builtin_bit_cast(f16x2, K1[d]);
            float k00 = (float)h0[0], k01 = (float)h0[1];
            float k10 = (float)h1[0], k11 = (float)h1[1];
            float v0 = (float)vv[0], v1v = (float)vv[1];
            l0 = fmaf((1.f - (15.f - __log2f(k00)) * rk2) * k00, v0, l0);
            l0 = fmaf((1.f - (15.f - __log2f(k01)) * rk2) * k01, v1v, l0);
            l1 = fmaf((1.f - (15.f - __log2f(k10)) * rk2) * k10, v0, l1);
            l1 = fmaf((1.f - (15.f - __log2f(k11)) * rk2) * k11, v1v, l1);
        }
        lsum = l0 * u0 + l1 * u1;
    }
    #pragma unroll
    for (int off = 32; off; off >>= 1) lsum += __shfl_down(lsum, off);
    if (l == 0) ws[OFF_LOGITS + pair] = lsum * (0.125f / 4.f);
}

// ---------------- K4: log-softmax + loss --------------------------------
__global__ void k_final(const int* __restrict__ label, const float* __restrict__ ws,
                        float* __restrict__ out) {
    int t = threadIdx.x;
    float contrib = 0.f;
    if (t < NQ) {
        float lg[NW];
        #pragma unroll
        for (int n = 0; n < NW; ++n) lg[n] = ws[OFF_LOGITS + t * NW + n];
        float mx = lg[0];
        #pragma unroll
        for (int n = 1; n < NW; ++n) mx = fmaxf(mx, lg[n]);
        float s = 0.f;
        #pragma unroll
        for (int n = 0; n < NW; ++n) s += expf(lg[n] - mx);
        float lse = mx + logf(s);
        int lab = label[t];
        #pragma unroll
        for (int n = 0; n < NW; ++n) {
            float lp = lg[n] - lse;
            out[t * NW + n] = lp;
            if (n == lab) contrib = -lp;
        }
    }
    #pragma unroll
    for (int off = 32; off; off >>= 1) contrib += __shfl_down(contrib, off);
    __shared__ float red[6];
    if ((t & 63) == 0) red[t >> 6] = contrib;
    __syncthreads();
    if (t == 0) {
        float s = 0.f;
        #pragma unroll
        for (int i = 0; i < 6; ++i) s += red[i];
        out[NQ * NW] = s * (1.f / NQ);
    }
}

extern "C" void kernel_launch(void* const* d_in, const int* in_sizes, int n_in,
                              void* d_out, int out_size, void* d_ws, size_t ws_size,
                              hipStream_t stream) {
    const float* feat  = (const float*)d_in[0];
    const int*   label = (const int*)d_in[1];
    float* out = (float*)d_out;
    float* ws  = (float*)d_ws;
    const float* query = feat + (size_t)NS * CCH * PP;
    bool fast = ws_size >= REQ2_WS_BYTES;

    k_proto<<<NW * CCH, 128, 0, stream>>>(feat, ws);
    k_qstat<<<NQ, 256, 0, stream>>>(query, ws + OFF_QSQ, ws + OFF_QAVG,
                                    fast ? (uint*)(ws + OFF_QF16) : (uint*)0);
    k_qstat<<<NW, 256, 0, stream>>>(ws + OFF_PROTO, ws + OFF_PSQ, (float*)0, (uint*)0);
    k_conv<<<NW * 16, 256, 0, stream>>>(ws + OFF_PROTO, ws + OFF_PAVG, (uint*)(ws + OFF_PF16));
    if (fast) {
        k_qpad<<<NQ, 256, 0, stream>>>(ws + OFF_QAVG, (uint*)(ws + OFF_QF16));
        k_cost2<<<NPAIR, 256, 0, stream>>>(ws);
        k_sink<<<NPAIR, 64, 0, stream>>>(ws);
    } else {
        k_costL<<<NPAIR, 256, 0, stream>>>(query, ws);
        k_sink<<<NPAIR, 64, 0, stream>>>(ws);
    }
    k_final<<<1, 384, 0, stream>>>(label, ws, out);
}

// Round 17
// 231.452 us; speedup vs baseline: 3.8770x; 3.8770x over previous
//
#include <hip/hip_runtime.h>
#include <math.h>

#define NW   5
#define PRJ  14
#define CCH  512
#define PP   100
#define NQ   375
#define NS   70
#define NPAIR (NQ*NW)

// ws offsets (floats)
#define OFF_PROTO   0          // 256000
#define OFF_PAVG    256000     // 2560
#define OFF_QAVG    258560     // 192000
#define OFF_QSQ     450560     // 37500
#define OFF_PSQ     488060     // 500
#define OFF_LOGITS  488560     // 1875
#define OFF_PF16    490440     // 163840
#define OFF_AUX     654280     // 1875*204 = 382500
#define OFF_KG      1036780    // 18,750,000 dwords
#define OFF_QF16    19786844   // 375*16*2048 = 12,288,000 dwords
#define REQ2_WS_BYTES ((size_t)(OFF_QF16 + 12288000 + 64) * 4)

typedef float f32x16 __attribute__((ext_vector_type(16)));
typedef _Float16 f16x2 __attribute__((ext_vector_type(2)));
typedef _Float16 f16x8 __attribute__((ext_vector_type(8)));

__device__ __forceinline__ int SWZ(int n) { return n ^ ((n >> 2) & 7); }

// ---------------- K1: proto = mean over shots; proto_avg ----------------
__global__ void k_proto(const float* __restrict__ feat, float* __restrict__ ws) {
    int nc = blockIdx.x;
    int n  = nc >> 9;
    int p  = threadIdx.x;
    float s = 0.f;
    if (p < PP) {
        const float* base = feat + (size_t)((n * PRJ) * CCH) * PP + (size_t)(nc & 511) * PP + p;
        #pragma unroll
        for (int k = 0; k < PRJ; ++k) s += base[(size_t)k * CCH * PP];
        s *= (1.f / PRJ);
        ws[OFF_PROTO + nc * PP + p] = s;
    }
    float v = (p < PP) ? s : 0.f;
    #pragma unroll
    for (int off = 32; off; off >>= 1) v += __shfl_down(v, off);
    __shared__ float red[2];
    if ((threadIdx.x & 63) == 0) red[threadIdx.x >> 6] = v;
    __syncthreads();
    if (threadIdx.x == 0) ws[OFF_PAVG + nc] = (red[0] + red[1]) * (1.f / PP);
}

// ------- K2: per-image transpose-stats (+ optional fused f16-image emit)
__global__ __launch_bounds__(256) void k_qstat(const float* __restrict__ src,
                                               float* __restrict__ dst_sq,
                                               float* __restrict__ dst_avg,
                                               uint* __restrict__ qimg) {
    __shared__ __align__(16) float t[6400];
    int b = blockIdx.x, tid = threadIdx.x;
    const float* base = src + (size_t)b * CCH * PP;
    uint* imgb = qimg ? (qimg + (size_t)b * 32768) : (uint*)0;
    float qsq = 0.f;
    for (int c0 = 0; c0 < CCH; c0 += 64) {
        __syncthreads();
        const float4* g = (const float4*)(base + (size_t)c0 * PP);
        for (int i = tid; i < 1600; i += 256) ((float4*)t)[i] = g[i];
        __syncthreads();
        if (tid < PP) {
            #pragma unroll 8
            for (int c = 0; c < 64; ++c) { float x = t[c * PP + tid]; qsq = fmaf(x, x, qsq); }
        } else if (tid >= 128 && tid < 192) {
            int ch = tid - 128;
            const float4* row = (const float4*)(t + ch * PP);
            float s = 0.f;
            #pragma unroll
            for (int i = 0; i < 25; ++i) { float4 v = row[i]; s += (v.x + v.y) + (v.z + v.w); }
            if (dst_avg) dst_avg[(size_t)b * CCH + c0 + ch] = s * (1.f / PP);
        }
        if (imgb) {
            for (int i = tid; i < 3200; i += 256) {
                int cpl = i / 100, col = i - cpl * 100;
                int cp = (c0 >> 1) + cpl;
                int kt = cp >> 4, cpk = cp & 15;
                float a0 = t[(2 * cpl) * 100 + col];
                float a1 = t[(2 * cpl + 1) * 100 + col];
                uint pk = __builtin_bit_cast(uint, __builtin_amdgcn_cvt_pkrtz(a0, a1));
                imgb[(size_t)kt * 2048 + ((((cpk >> 2) << 7) | SWZ(col)) * 4 + (cpk & 3))] = pk;
            }
        }
    }
    if (tid < PP) dst_sq[b * PP + tid] = qsq;
}

// ------- K2c: fill avg row + pad slots of query images -------
__global__ __launch_bounds__(256) void k_qpad(const float* __restrict__ avg,
                                              uint* __restrict__ dst) {
    int b = blockIdx.x;
    int tid = threadIdx.x;
    uint* img = dst + (size_t)b * 32768;
    const float* av = avg + (size_t)b * CCH;
    if (tid < 256) {
        int kt = tid >> 4, cp = tid & 15;
        float a0 = av[kt * 32 + 2 * cp], a1 = av[kt * 32 + 2 * cp + 1];
        uint pk = __builtin_bit_cast(uint, __builtin_amdgcn_cvt_pkrtz(a0, a1));
        img[(size_t)kt * 2048 + (((cp >> 2) << 7) | 101) * 4 + (cp & 3)] = pk;
    }
    for (int i = tid; i < 6912; i += 256) {
        int dw = i & 3; int t2 = i >> 2;
        int k4 = t2 & 3; int t3 = t2 >> 2;
        int s_i = t3 % 27; int kt = t3 / 27;
        int s = 100 + s_i + (s_i >= 1 ? 1 : 0);   // skip slot 101
        uint val = (s == 100) ? 0x3C003C00u : 0u;
        img[(size_t)kt * 2048 + (((k4) << 7) | s) * 4 + dw] = val;
    }
}

// ------- K2b: convert f32 image -> SWZ'd f16 kt-images (protos) -------
__global__ __launch_bounds__(256) void k_conv(const float* __restrict__ src,
                                              const float* __restrict__ avg,
                                              uint* __restrict__ dst) {
    int b = blockIdx.x;          // id*16 + kt
    int id = b >> 4, kt = b & 15;
    int tid = threadIdx.x;
    int c0 = kt * 32;
    uint* img = dst + (size_t)b * 2048;
    const float* pb = src + (size_t)id * CCH * PP;
    const float* pavg = avg + (size_t)id * CCH;
    for (int i = tid; i < 1600; i += 256) {
        int cp = i / 100, col = i - cp * 100;
        float a0 = pb[(size_t)(c0 + 2 * cp) * PP + col];
        float a1 = pb[(size_t)(c0 + 2 * cp + 1) * PP + col];
        uint pk = __builtin_bit_cast(uint, __builtin_amdgcn_cvt_pkrtz(a0, a1));
        img[(((cp >> 2) << 7) | SWZ(col)) * 4 + (cp & 3)] = pk;
    }
    if (tid < 16) {
        int cp = tid;
        float a0 = pavg[c0 + 2 * cp], a1 = pavg[c0 + 2 * cp + 1];
        uint pk = __builtin_bit_cast(uint, __builtin_amdgcn_cvt_pkrtz(a0, a1));
        img[(((cp >> 2) << 7) | 101) * 4 + (cp & 3)] = pk;
    }
    for (int i = tid; i < 448; i += 256) {
        int dw = i & 3; int t2 = i >> 2;
        int s_i = t2 % 28; int k4 = t2 / 28;
        int s = 100 + s_i;
        if (s == 101) continue;
        img[(((k4) << 7) | s) * 4 + dw] = (s == 100) ? 0x3C003C00u : 0u;
    }
}

// ------- K3a-direct: MFMA operands straight from global images ----------
// per-kt batched loads (10 in flight) then 8 MFMAs; (256,3) for reg headroom
__global__ __launch_bounds__(256, 3) void k_cost2(float* __restrict__ ws) {
    __shared__ __align__(16) char SH[22400];
    __shared__ float wrL[PP], wcL[PP], qnl[PP], pnl[PP], sqv[PP], spv[PP];
    __shared__ float red[8];
    uint* Kst = (uint*)SH;

    int p_ = blockIdx.x;
    int xcd = p_ & 7, off_ = p_ >> 3;
    int pair = (xcd < 3) ? (xcd * 235 + off_) : (705 + (xcd - 3) * 234 + off_);

    int m = pair / NW;
    int n = pair - m * NW;
    int tid = threadIdx.x;
    int lane = tid & 63, wid = tid >> 6;
    int lrow = lane & 31, lhi = lane >> 5;

    const char* qimg = (const char*)((const uint*)(ws + OFF_QF16) + (size_t)m * 16 * 2048);
    const char* pimg = (const char*)((const uint*)(ws + OFF_PF16) + (size_t)n * 16 * 2048);

    f32x16 acc[4];
    #pragma unroll
    for (int tc = 0; tc < 4; ++tc)
        #pragma unroll
        for (int e = 0; e < 16; ++e) acc[tc][e] = 0.f;

    int arow16 = SWZ(32 * wid + lrow) * 16;
    int bcol16[4];
    #pragma unroll
    for (int tc = 0; tc < 4; ++tc) bcol16[tc] = SWZ(32 * tc + lrow) * 16;

    #pragma unroll 2
    for (int kt = 0; kt < 16; ++kt) {
        const char* qk = qimg + kt * 8192;
        const char* pk = pimg + kt * 8192;
        int kb0 = lhi * 2048;
        int kb1 = (2 + lhi) * 2048;
        // issue all 10 loads for this kt before any MFMA
        f16x8 ah0 = *(const f16x8*)(qk + kb0 + arow16);
        f16x8 b00 = *(const f16x8*)(pk + kb0 + bcol16[0]);
        f16x8 b01 = *(const f16x8*)(pk + kb0 + bcol16[1]);
        f16x8 b02 = *(const f16x8*)(pk + kb0 + bcol16[2]);
        f16x8 b03 = *(const f16x8*)(pk + kb0 + bcol16[3]);
        f16x8 ah1 = *(const f16x8*)(qk + kb1 + arow16);
        f16x8 b10 = *(const f16x8*)(pk + kb1 + bcol16[0]);
        f16x8 b11 = *(const f16x8*)(pk + kb1 + bcol16[1]);
        f16x8 b12 = *(const f16x8*)(pk + kb1 + bcol16[2]);
        f16x8 b13 = *(const f16x8*)(pk + kb1 + bcol16[3]);
        acc[0] = __builtin_amdgcn_mfma_f32_32x32x16_f16(ah0, b00, acc[0], 0, 0, 0);
        acc[1] = __builtin_amdgcn_mfma_f32_32x32x16_f16(ah0, b01, acc[1], 0, 0, 0);
        acc[2] = __builtin_amdgcn_mfma_f32_32x32x16_f16(ah0, b02, acc[2], 0, 0, 0);
        acc[3] = __builtin_amdgcn_mfma_f32_32x32x16_f16(ah0, b03, acc[3], 0, 0, 0);
        acc[0] = __builtin_amdgcn_mfma_f32_32x32x16_f16(ah1, b10, acc[0], 0, 0, 0);
        acc[1] = __builtin_amdgcn_mfma_f32_32x32x16_f16(ah1, b11, acc[1], 0, 0, 0);
        acc[2] = __builtin_amdgcn_mfma_f32_32x32x16_f16(ah1, b12, acc[2], 0, 0, 0);
        acc[3] = __builtin_amdgcn_mfma_f32_32x32x16_f16(ah1, b13, acc[3], 0, 0, 0);
    }

    // extract w1 (col 100), sum_q (col 101), w2 (row 100), sum_p (row 101)
    if ((lane & 31) == 4 || (lane & 31) == 5) {
        float* dst = ((lane & 31) == 4) ? wrL : sqv;
        #pragma unroll
        for (int reg = 0; reg < 16; ++reg) {
            int row = 32 * wid + (reg & 3) + 8 * (reg >> 2) + 4 * lhi;
            if (row < PP) dst[row] = acc[3][reg];
        }
    }
    if (wid == 3 && lhi == 1) {
        #pragma unroll
        for (int tc = 0; tc < 4; ++tc) {
            int col = 32 * tc + lrow;
            if (col < PP) { wcL[col] = acc[tc][0]; spv[col] = acc[tc][1]; }
        }
    }
    __syncthreads();

    float v1 = 0.f, v2 = 0.f;
    if (tid < PP) {
        v1 = fmaxf(wrL[tid], 0.f) + 0.00101f;
        v2 = fmaxf(wcL[tid], 0.f) + 0.00101f;
    }
    float s1 = v1, s2 = v2;
    #pragma unroll
    for (int off = 32; off; off >>= 1) { s1 += __shfl_down(s1, off); s2 += __shfl_down(s2, off); }
    if ((tid & 63) == 0) { red[tid >> 6] = s1; red[4 + (tid >> 6)] = s2; }
    __syncthreads();
    float t1 = red[0] + red[1], t2 = red[4] + red[5];
    if (tid < PP) {
        wrL[tid] = v1 * (100.f / t1) * 4.f;
        wcL[tid] = v2 * (100.f / t2) * 4.f;
        float sq = sqv[tid], sp = spv[tid];
        qnl[tid] = ws[OFF_QSQ + m * PP + tid] - sq * sq * (1.f / 512.f);
        pnl[tid] = ws[OFF_PSQ + n * PP + tid] - sp * sp * (1.f / 512.f);
    }
    __syncthreads();

    float spc[4], pnc[4];
    #pragma unroll
    for (int tc = 0; tc < 4; ++tc) {
        int col = 32 * tc + lrow;
        bool cv = col < PP;
        spc[tc] = cv ? spv[col] : 0.f;
        pnc[tc] = cv ? pnl[col] : 0.f;
    }
    float mymax = -1e30f;
    #pragma unroll
    for (int reg = 0; reg < 16; ++reg) {
        int row = 32 * wid + (reg & 3) + 8 * (reg >> 2) + 4 * lhi;
        bool rv = row < PP;
        float sqr = rv ? sqv[row] : 0.f;
        float qnr = rv ? qnl[row] : 0.f;
        #pragma unroll
        for (int tc = 0; tc < 4; ++tc) {
            float sqd = qnr + pnc[tc] - 2.f * (acc[tc][reg] - sqr * spc[tc] * (1.f / 512.f));
            acc[tc][reg] = sqd;
            int col = 32 * tc + lrow;
            if (rv && col < PP) mymax = fmaxf(mymax, sqd);
        }
    }
    #pragma unroll
    for (int off = 32; off; off >>= 1) mymax = fmaxf(mymax, __shfl_down(mymax, off));
    __syncthreads();
    if (lane == 0) red[wid] = mymax;
    __syncthreads();
    float scale = fmaxf(fmaxf(red[0], red[1]), fmaxf(red[2], red[3])) + 1e-6f;
    float k2 = (1.f / scale) * (20.f * 1.44269504088896f);

    #pragma unroll
    for (int tc = 0; tc < 4; ++tc) {
        float kv[16];
        #pragma unroll
        for (int reg = 0; reg < 16; ++reg) kv[reg] = exp2f(fmaf(-acc[tc][reg], k2, 15.f));
        int col = 32 * tc + lrow;
        #pragma unroll
        for (int reg = 0; reg < 16; ++reg) {
            float pv = __shfl_xor(kv[reg], 1);
            int row = 32 * wid + (reg & 3) + 8 * (reg >> 2) + 4 * lhi;
            if (!(lane & 1) && row < PP && col < PP) {
                int j = col >> 1;
                int dw = (j < 25) ? j : (j + 3);
                uint pk = __builtin_bit_cast(uint, __builtin_amdgcn_cvt_pkrtz(kv[reg], pv));
                Kst[row * 56 + dw] = pk;
            }
        }
    }
    __syncthreads();

    // gather rows/cols; coalesced Kg layout: K[j][row] @0, KT[rp][col] @5000
    int r_ = tid >> 1, hf = tid & 1;
    bool sact = tid < 200;
    if (sact) {
        uint Kr[25], KTr[25];
        const uint* rp = Kst + r_ * 56 + 28 * hf;
        #pragma unroll
        for (int q = 0; q < 25; ++q) Kr[q] = rp[q];
        int j = r_ >> 1;
        int dwc = (j < 25) ? j : (j + 3);
        int sh = (r_ & 1) * 16;
        const uint* cp0 = Kst + (50 * hf) * 56 + dwc;
        #pragma unroll
        for (int q = 0; q < 25; ++q) {
            uint d0 = cp0[(2 * q) * 56];
            uint d1 = cp0[(2 * q + 1) * 56];
            KTr[q] = ((d0 >> sh) & 0xFFFFu) | (((d1 >> sh) & 0xFFFFu) << 16);
        }
        uint* kg = (uint*)(ws + OFF_KG) + (size_t)pair * 10000;
        #pragma unroll
        for (int q = 0; q < 25; ++q) kg[(25 * hf + q) * 100 + r_] = Kr[q];
        #pragma unroll
        for (int q = 0; q < 25; ++q) kg[5000 + (25 * hf + q) * 100 + r_] = KTr[q];
    }
    float* aux = ws + OFF_AUX + (size_t)pair * 204;
    if (tid < PP) { aux[tid] = wrL[tid]; aux[100 + tid] = wcL[tid]; }
    if (tid == 0) aux[200] = scale;
}

// ------- K3a-fallback: LDS-staging variant (same new Kg layout) -------
__global__ __launch_bounds__(256, 4) void k_costL(const float* __restrict__ query,
                                                  float* __restrict__ ws) {
    __shared__ __align__(16) char SH[22400];
    __shared__ float wrL[PP], wcL[PP], qnl[PP], pnl[PP], sqv[PP], spv[PP];
    __shared__ float red[8];
    uint* Kst = (uint*)SH;

    int p_ = blockIdx.x;
    int xcd = p_ & 7, off_ = p_ >> 3;
    int pair = (xcd < 3) ? (xcd * 235 + off_) : (705 + (xcd - 3) * 234 + off_);

    int m = pair / NW;
    int n = pair - m * NW;
    int tid = threadIdx.x;
    int lane = tid & 63, wid = tid >> 6;
    int lrow = lane & 31, lhi = lane >> 5;

    const float* qb = query + (size_t)m * CCH * PP;
    const float* qavg_g = ws + OFF_QAVG + (size_t)m * CCH;
    const uint* pimg = (const uint*)(ws + OFF_PF16) + (size_t)n * 16 * 2048;

    for (int idx = tid; idx < 112; idx += 256) {
        int s_i = idx % 28; int k4 = idx / 28;
        int s = 100 + s_i;
        if (s == 101) continue;
        uint4 val = (s == 100)
                  ? make_uint4(0x3C003C00u, 0x3C003C00u, 0x3C003C00u, 0x3C003C00u)
                  : make_uint4(0u, 0u, 0u, 0u);
        *(uint4*)&SH[(k4 * 128 + s) * 16] = val;
    }

    f32x16 acc[4];
    #pragma unroll
    for (int tc = 0; tc < 4; ++tc)
        #pragma unroll
        for (int e = 0; e < 16; ++e) acc[tc][e] = 0.f;

    int arow16 = SWZ(32 * wid + lrow) * 16;
    int bcol16[4];
    #pragma unroll
    for (int tc = 0; tc < 4; ++tc) bcol16[tc] = SWZ(32 * tc + lrow) * 16;

    for (int kt = 0; kt < 16; ++kt) {
        int c0 = kt * 32;
        for (int idx = tid; idx < 400; idx += 256) {
            int cp = idx / 25, n4 = idx - cp * 25;
            const float* src = qb + (size_t)(c0 + 2 * cp) * PP + n4 * 4;
            float4 x0 = *(const float4*)src;
            float4 x1 = *(const float4*)(src + PP);
            const float* p0 = (const float*)&x0;
            const float* p1 = (const float*)&x1;
            int basedw = ((cp >> 2) << 7);
            int dwb = (cp & 3) * 4;
            #pragma unroll
            for (int i4 = 0; i4 < 4; ++i4) {
                int node = n4 * 4 + i4;
                uint pk = __builtin_bit_cast(uint, __builtin_amdgcn_cvt_pkrtz(p0[i4], p1[i4]));
                *(uint*)&SH[(basedw + SWZ(node)) * 16 + dwb] = pk;
            }
        }
        if (tid < 16) {
            int cp = tid;
            uint pk = __builtin_bit_cast(uint,
                __builtin_amdgcn_cvt_pkrtz(qavg_g[c0 + 2 * cp], qavg_g[c0 + 2 * cp + 1]));
            *(uint*)&SH[(((cp >> 2) << 7) + 101) * 16 + (cp & 3) * 4] = pk;
        }
        {
            const float4* gB = (const float4*)(pimg + (size_t)kt * 2048);
            float4* sB = (float4*)&SH[8192];
            for (int i = tid; i < 512; i += 256) sB[i] = gB[i];
        }
        __syncthreads();
        __builtin_amdgcn_s_setprio(1);
        #pragma unroll
        for (int s = 0; s < 2; ++s) {
            int kb = (2 * s + lhi) * 2048;
            f16x8 ah = *(const f16x8*)&SH[kb + arow16];
            #pragma unroll
            for (int tc = 0; tc < 4; ++tc) {
                f16x8 bh = *(const f16x8*)&SH[8192 + kb + bcol16[tc]];
                acc[tc] = __builtin_amdgcn_mfma_f32_32x32x16_f16(ah, bh, acc[tc], 0, 0, 0);
            }
        }
        __builtin_amdgcn_s_setprio(0);
        __syncthreads();
    }

    if ((lane & 31) == 4 || (lane & 31) == 5) {
        float* dst = ((lane & 31) == 4) ? wrL : sqv;
        #pragma unroll
        for (int reg = 0; reg < 16; ++reg) {
            int row = 32 * wid + (reg & 3) + 8 * (reg >> 2) + 4 * lhi;
            if (row < PP) dst[row] = acc[3][reg];
        }
    }
    if (wid == 3 && lhi == 1) {
        #pragma unroll
        for (int tc = 0; tc < 4; ++tc) {
            int col = 32 * tc + lrow;
            if (col < PP) { wcL[col] = acc[tc][0]; spv[col] = acc[tc][1]; }
        }
    }
    __syncthreads();

    float v1 = 0.f, v2 = 0.f;
    if (tid < PP) {
        v1 = fmaxf(wrL[tid], 0.f) + 0.00101f;
        v2 = fmaxf(wcL[tid], 0.f) + 0.00101f;
    }
    float s1 = v1, s2 = v2;
    #pragma unroll
    for (int off = 32; off; off >>= 1) { s1 += __shfl_down(s1, off); s2 += __shfl_down(s2, off); }
    if ((tid & 63) == 0) { red[tid >> 6] = s1; red[4 + (tid >> 6)] = s2; }
    __syncthreads();
    float t1 = red[0] + red[1], t2 = red[4] + red[5];
    if (tid < PP) {
        wrL[tid] = v1 * (100.f / t1) * 4.f;
        wcL[tid] = v2 * (100.f / t2) * 4.f;
        float sq = sqv[tid], sp = spv[tid];
        qnl[tid] = ws[OFF_QSQ + m * PP + tid] - sq * sq * (1.f / 512.f);
        pnl[tid] = ws[OFF_PSQ + n * PP + tid] - sp * sp * (1.f / 512.f);
    }
    __syncthreads();

    float spc[4], pnc[4];
    #pragma unroll
    for (int tc = 0; tc < 4; ++tc) {
        int col = 32 * tc + lrow;
        bool cv = col < PP;
        spc[tc] = cv ? spv[col] : 0.f;
        pnc[tc] = cv ? pnl[col] : 0.f;
    }
    float mymax = -1e30f;
    #pragma unroll
    for (int reg = 0; reg < 16; ++reg) {
        int row = 32 * wid + (reg & 3) + 8 * (reg >> 2) + 4 * lhi;
        bool rv = row < PP;
        float sqr = rv ? sqv[row] : 0.f;
        float qnr = rv ? qnl[row] : 0.f;
        #pragma unroll
        for (int tc = 0; tc < 4; ++tc) {
            float sqd = qnr + pnc[tc] - 2.f * (acc[tc][reg] - sqr * spc[tc] * (1.f / 512.f));
            acc[tc][reg] = sqd;
            int col = 32 * tc + lrow;
            if (rv && col < PP) mymax = fmaxf(mymax, sqd);
        }
    }
    #pragma unroll
    for (int off = 32; off; off >>= 1) mymax = fmaxf(mymax, __shfl_down(mymax, off));
    __syncthreads();
    if (lane == 0) red[wid] = mymax;
    __syncthreads();
    float scale = fmaxf(fmaxf(red[0], red[1]), fmaxf(red[2], red[3])) + 1e-6f;
    float k2 = (1.f / scale) * (20.f * 1.44269504088896f);

    #pragma unroll
    for (int tc = 0; tc < 4; ++tc) {
        float kv[16];
        #pragma unroll
        for (int reg = 0; reg < 16; ++reg) kv[reg] = exp2f(fmaf(-acc[tc][reg], k2, 15.f));
        int col = 32 * tc + lrow;
        #pragma unroll
        for (int reg = 0; reg < 16; ++reg) {
            float pv = __shfl_xor(kv[reg], 1);
            int row = 32 * wid + (reg & 3) + 8 * (reg >> 2) + 4 * lhi;
            if (!(lane & 1) && row < PP && col < PP) {
                int j = col >> 1;
                int dw = (j < 25) ? j : (j + 3);
                uint pk = __builtin_bit_cast(uint, __builtin_amdgcn_cvt_pkrtz(kv[reg], pv));
                Kst[row * 56 + dw] = pk;
            }
        }
    }
    __syncthreads();

    int r_ = tid >> 1, hf = tid & 1;
    bool sact = tid < 200;
    if (sact) {
        uint Kr[25], KTr[25];
        const uint* rp = Kst + r_ * 56 + 28 * hf;
        #pragma unroll
        for (int q = 0; q < 25; ++q) Kr[q] = rp[q];
        int j = r_ >> 1;
        int dwc = (j < 25) ? j : (j + 3);
        int sh = (r_ & 1) * 16;
        const uint* cp0 = Kst + (50 * hf) * 56 + dwc;
        #pragma unroll
        for (int q = 0; q < 25; ++q) {
            uint d0 = cp0[(2 * q) * 56];
            uint d1 = cp0[(2 * q + 1) * 56];
            KTr[q] = ((d0 >> sh) & 0xFFFFu) | (((d1 >> sh) & 0xFFFFu) << 16);
        }
        uint* kg = (uint*)(ws + OFF_KG) + (size_t)pair * 10000;
        #pragma unroll
        for (int q = 0; q < 25; ++q) kg[(25 * hf + q) * 100 + r_] = Kr[q];
        #pragma unroll
        for (int q = 0; q < 25; ++q) kg[5000 + (25 * hf + q) * 100 + r_] = KTr[q];
    }
    float* aux = ws + OFF_AUX + (size_t)pair * 204;
    if (tid < PP) { aux[tid] = wrL[tid]; aux[100 + tid] = wcL[tid]; }
    if (tid == 0) aux[200] = scale;
}

// ------- K3b: k_sink — one wave per pair, register-resident K -------
__global__ __launch_bounds__(64, 2) void k_sink(float* __restrict__ ws) {
    __shared__ __align__(16) uint uhL[52], vhL[52];
    int pair = blockIdx.x;
    int l = threadIdx.x;
    bool act = l < 50;

    const float* aux = ws + OFF_AUX + (size_t)pair * 204;
    float wr0 = 0.f, wr1 = 0.f, wc0 = 0.f, wc1 = 0.f;
    if (act) {
        wr0 = aux[2 * l]; wr1 = aux[2 * l + 1];
        wc0 = aux[100 + 2 * l]; wc1 = aux[101 + 2 * l];
    }
    float scale = aux[200];
    float rk2 = scale * (1.f / (20.f * 1.44269504088896f));

    uint K0[50], K1[50], T0[50], T1[50];
    {
        const uint2* kg2 = (const uint2*)((const uint*)(ws + OFF_KG) + (size_t)pair * 10000);
        int ll = act ? l : 0;
        #pragma unroll
        for (int j = 0; j < 50; ++j) { uint2 kk = kg2[j * 50 + ll]; K0[j] = kk.x; K1[j] = kk.y; }
        #pragma unroll
        for (int j = 0; j < 50; ++j) { uint2 kk = kg2[2500 + j * 50 + ll]; T0[j] = kk.x; T1[j] = kk.y; }
    }
    if (l < 52) { vhL[l] = (l < 50) ? 0x3C003C00u : 0u; uhL[l] = 0u; }
    __syncthreads();

    float u0 = 0.f, u1 = 0.f;
    for (int it = 0; it < 50; ++it) {
        if (act) {
            const uint4* vp4 = (const uint4*)vhL;
            float a0 = 0.f, b0 = 0.f, a1 = 0.f, b1 = 0.f;
            #pragma unroll
            for (int d4 = 0; d4 < 12; ++d4) {
                uint4 V = vp4[d4];
                a0 = __builtin_amdgcn_fdot2(__builtin_bit_cast(f16x2, K0[4*d4+0]), __builtin_bit_cast(f16x2, V.x), a0, false);
                b0 = __builtin_amdgcn_fdot2(__builtin_bit_cast(f16x2, K0[4*d4+1]), __builtin_bit_cast(f16x2, V.y), b0, false);
                a0 = __builtin_amdgcn_fdot2(__builtin_bit_cast(f16x2, K0[4*d4+2]), __builtin_bit_cast(f16x2, V.z), a0, false);
                b0 = __builtin_amdgcn_fdot2(__builtin_bit_cast(f16x2, K0[4*d4+3]), __builtin_bit_cast(f16x2, V.w), b0, false);
                a1 = __builtin_amdgcn_fdot2(__builtin_bit_cast(f16x2, K1[4*d4+0]), __builtin_bit_cast(f16x2, V.x), a1, false);
                b1 = __builtin_amdgcn_fdot2(__builtin_bit_cast(f16x2, K1[4*d4+1]), __builtin_bit_cast(f16x2, V.y), b1, false);
                a1 = __builtin_amdgcn_fdot2(__builtin_bit_cast(f16x2, K1[4*d4+2]), __builtin_bit_cast(f16x2, V.z), a1, false);
                b1 = __builtin_amdgcn_fdot2(__builtin_bit_cast(f16x2, K1[4*d4+3]), __builtin_bit_cast(f16x2, V.w), b1, false);
            }
            {
                uint v48 = vhL[48], v49 = vhL[49];
                a0 = __builtin_amdgcn_fdot2(__builtin_bit_cast(f16x2, K0[48]), __builtin_bit_cast(f16x2, v48), a0, false);
                b0 = __builtin_amdgcn_fdot2(__builtin_bit_cast(f16x2, K0[49]), __builtin_bit_cast(f16x2, v49), b0, false);
                a1 = __builtin_amdgcn_fdot2(__builtin_bit_cast(f16x2, K1[48]), __builtin_bit_cast(f16x2, v48), a1, false);
                b1 = __builtin_amdgcn_fdot2(__builtin_bit_cast(f16x2, K1[49]), __builtin_bit_cast(f16x2, v49), b1, false);
            }
            u0 = fminf(wr0 * __builtin_amdgcn_rcpf(a0 + b0), 60000.f);
            u1 = fminf(wr1 * __builtin_amdgcn_rcpf(a1 + b1), 60000.f);
            uhL[l] = __builtin_bit_cast(uint, __builtin_amdgcn_cvt_pkrtz(u0, u1));
        }
        __syncthreads();
        if (act) {
            const uint4* up4 = (const uint4*)uhL;
            float a0 = 0.f, b0 = 0.f, a1 = 0.f, b1 = 0.f;
            #pragma unroll
            for (int d4 = 0; d4 < 12; ++d4) {
                uint4 U = up4[d4];
                a0 = __builtin_amdgcn_fdot2(__builtin_bit_cast(f16x2, T0[4*d4+0]), __builtin_bit_cast(f16x2, U.x), a0, false);
                b0 = __builtin_amdgcn_fdot2(__builtin_bit_cast(f16x2, T0[4*d4+1]), __builtin_bit_cast(f16x2, U.y), b0, false);
                a0 = __builtin_amdgcn_fdot2(__builtin_bit_cast(f16x2, T0[4*d4+2]), __builtin_bit_cast(f16x2, U.z), a0, false);
                b0 = __builtin_amdgcn_fdot2(__builtin_bit_cast(f16x2, T0[4*d4+3]), __builtin_bit_cast(f16x2, U.w), b0, false);
                a1 = __builtin_amdgcn_fdot2(__builtin_bit_cast(f16x2, T1[4*d4+0]), __builtin_bit_cast(f16x2, U.x), a1, false);
                b1 = __builtin_amdgcn_fdot2(__builtin_bit_cast(f16x2, T1[4*d4+1]), __builtin_bit_cast(f16x2, U.y), b1, false);
                a1 = __builtin_amdgcn_fdot2(__builtin_bit_cast(f16x2, T1[4*d4+2]), __builtin_bit_cast(f16x2, U.z), a1, false);
                b1 = __builtin_amdgcn_fdot2(__builtin_bit_cast(f16x2, T1[4*d4+3]), __builtin_bit_cast(f16x2, U.w), b1, false);
            }
            {
                uint u48 = uhL[48], u49 = uhL[49];
                a0 = __builtin_amdgcn_fdot2(__builtin_bit_cast(f16x2, T0[48]), __builtin_bit_cast(f16x2, u48), a0, false);
                b0 = __builtin_amdgcn_fdot2(__builtin_bit_cast(f16x2, T0[49]), __builtin_bit_cast(f16x2, u49), b0, false);
                a1 = __builtin_amdgcn_fdot2(__builtin_bit_cast(f16x2, T1[48]), __builtin_bit_cast(f16x2, u48), a1, false);
                b1 = __builtin_amdgcn_fdot2(__builtin_bit_cast(f16x2, T1[49]), __builtin_bit_cast(f16x2, u49), b1, false);
            }
            float v0 = fminf(wc0 * __builtin_amdgcn_rcpf(a0 + b0), 60000.f);
            float v1n = fminf(wc1 * __builtin_amdgcn_rcpf(a1 + b1), 60000.f);
            vhL[l] = __builtin_bit_cast(uint, __builtin_amdgcn_cvt_pkrtz(v0, v1n));
        }
        __syncthreads();
    }

    float lsum = 0.f;
    if (act) {
        float l0 = 0.f, l1 = 0.f;
        #pragma unroll
        for (int d = 0; d < 50; ++d) {
            f16x2 vv = __builtin_bit_cast(f16x2, vhL[d]);
            f16x2 h0 = __builtin_bit_cast(f16x2, K0[d]);
            f16x2 h1 = __builtin_bit_cast(f16x2, K1[d]);
            float k00 = (float)h0[0], k01 = (float)h0[1];
            float k10 = (float)h1[0], k11 = (float)h1[1];
            float v0 = (float)vv[0], v1v = (float)vv[1];
            l0 = fmaf((1.f - (15.f - __log2f(k00)) * rk2) * k00, v0, l0);
            l0 = fmaf((1.f - (15.f - __log2f(k01)) * rk2) * k01, v1v, l0);
            l1 = fmaf((1.f - (15.f - __log2f(k10)) * rk2) * k10, v0, l1);
            l1 = fmaf((1.f - (15.f - __log2f(k11)) * rk2) * k11, v1v, l1);
        }
        lsum = l0 * u0 + l1 * u1;
    }
    #pragma unroll
    for (int off = 32; off; off >>= 1) lsum += __shfl_down(lsum, off);
    if (l == 0) ws[OFF_LOGITS + pair] = lsum * (0.125f / 4.f);
}

// ---------------- K4: log-softmax + loss --------------------------------
__global__ void k_final(const int* __restrict__ label, const float* __restrict__ ws,
                        float* __restrict__ out) {
    int t = threadIdx.x;
    float contrib = 0.f;
    if (t < NQ) {
        float lg[NW];
        #pragma unroll
        for (int n = 0; n < NW; ++n) lg[n] = ws[OFF_LOGITS + t * NW + n];
        float mx = lg[0];
        #pragma unroll
        for (int n = 1; n < NW; ++n) mx = fmaxf(mx, lg[n]);
        float s = 0.f;
        #pragma unroll
        for (int n = 0; n < NW; ++n) s += expf(lg[n] - mx);
        float lse = mx + logf(s);
        int lab = label[t];
        #pragma unroll
        for (int n = 0; n < NW; ++n) {
            float lp = lg[n] - lse;
            out[t * NW + n] = lp;
            if (n == lab) contrib = -lp;
        }
    }
    #pragma unroll
    for (int off = 32; off; off >>= 1) contrib += __shfl_down(contrib, off);
    __shared__ float red[6];
    if ((t & 63) == 0) red[t >> 6] = contrib;
    __syncthreads();
    if (t == 0) {
        float s = 0.f;
        #pragma unroll
        for (int i = 0; i < 6; ++i) s += red[i];
        out[NQ * NW] = s * (1.f / NQ);
    }
}

extern "C" void kernel_launch(void* const* d_in, const int* in_sizes, int n_in,
                              void* d_out, int out_size, void* d_ws, size_t ws_size,
                              hipStream_t stream) {
    const float* feat  = (const float*)d_in[0];
    const int*   label = (const int*)d_in[1];
    float* out = (float*)d_out;
    float* ws  = (float*)d_ws;
    const float* query = feat + (size_t)NS * CCH * PP;
    bool fast = ws_size >= REQ2_WS_BYTES;

    k_proto<<<NW * CCH, 128, 0, stream>>>(feat, ws);
    k_qstat<<<NQ, 256, 0, stream>>>(query, ws + OFF_QSQ, ws + OFF_QAVG,
                                    fast ? (uint*)(ws + OFF_QF16) : (uint*)0);
    k_qstat<<<NW, 256, 0, stream>>>(ws + OFF_PROTO, ws + OFF_PSQ, (float*)0, (uint*)0);
    k_conv<<<NW * 16, 256, 0, stream>>>(ws + OFF_PROTO, ws + OFF_PAVG, (uint*)(ws + OFF_PF16));
    if (fast) {
        k_qpad<<<NQ, 256, 0, stream>>>(ws + OFF_QAVG, (uint*)(ws + OFF_QF16));
        k_cost2<<<NPAIR, 256, 0, stream>>>(ws);
        k_sink<<<NPAIR, 64, 0, stream>>>(ws);
    } else {
        k_costL<<<NPAIR, 256, 0, stream>>>(query, ws);
        k_sink<<<NPAIR, 64, 0, stream>>>(ws);
    }
    k_final<<<1, 384, 0, stream>>>(label, ws, out);
}

// Round 18
// 223.895 us; speedup vs baseline: 4.0079x; 1.0337x over previous
//
#include <hip/hip_runtime.h>
#include <math.h>

#define NW   5
#define PRJ  14
#define CCH  512
#define PP   100
#define NQ   375
#define NS   70
#define NPAIR (NQ*NW)

// ws offsets (floats)
#define OFF_PROTO   0          // 256000
#define OFF_PAVG    256000     // 2560
#define OFF_QAVG    258560     // 192000
#define OFF_QSQ     450560     // 37500
#define OFF_PSQ     488060     // 500
#define OFF_LOGITS  488560     // 1875
#define OFF_PF16    490440     // 163840
#define OFF_AUX     654280     // 1875*204 = 382500
#define OFF_KG      1036780    // 18,750,000 dwords
#define OFF_QF16    19786844   // 375*16*2048 = 12,288,000 dwords
#define REQ2_WS_BYTES ((size_t)(OFF_QF16 + 12288000 + 64) * 4)

typedef float f32x16 __attribute__((ext_vector_type(16)));
typedef _Float16 f16x2 __attribute__((ext_vector_type(2)));
typedef _Float16 f16x8 __attribute__((ext_vector_type(8)));

__device__ __forceinline__ int SWZ(int n) { return n ^ ((n >> 2) & 7); }

// ---------------- K1: proto = mean over shots; proto_avg ----------------
__global__ void k_proto(const float* __restrict__ feat, float* __restrict__ ws) {
    int nc = blockIdx.x;
    int n  = nc >> 9;
    int p  = threadIdx.x;
    float s = 0.f;
    if (p < PP) {
        const float* base = feat + (size_t)((n * PRJ) * CCH) * PP + (size_t)(nc & 511) * PP + p;
        #pragma unroll
        for (int k = 0; k < PRJ; ++k) s += base[(size_t)k * CCH * PP];
        s *= (1.f / PRJ);
        ws[OFF_PROTO + nc * PP + p] = s;
    }
    float v = (p < PP) ? s : 0.f;
    #pragma unroll
    for (int off = 32; off; off >>= 1) v += __shfl_down(v, off);
    __shared__ float red[2];
    if ((threadIdx.x & 63) == 0) red[threadIdx.x >> 6] = v;
    __syncthreads();
    if (threadIdx.x == 0) ws[OFF_PAVG + nc] = (red[0] + red[1]) * (1.f / PP);
}

// ------- K2: per-image transpose-stats (+ optional fused f16-image emit)
__global__ __launch_bounds__(256) void k_qstat(const float* __restrict__ src,
                                               float* __restrict__ dst_sq,
                                               float* __restrict__ dst_avg,
                                               uint* __restrict__ qimg) {
    __shared__ __align__(16) float t[6400];
    int b = blockIdx.x, tid = threadIdx.x;
    const float* base = src + (size_t)b * CCH * PP;
    uint* imgb = qimg ? (qimg + (size_t)b * 32768) : (uint*)0;
    float qsq = 0.f;
    for (int c0 = 0; c0 < CCH; c0 += 64) {
        __syncthreads();
        const float4* g = (const float4*)(base + (size_t)c0 * PP);
        for (int i = tid; i < 1600; i += 256) ((float4*)t)[i] = g[i];
        __syncthreads();
        if (tid < PP) {
            #pragma unroll 8
            for (int c = 0; c < 64; ++c) { float x = t[c * PP + tid]; qsq = fmaf(x, x, qsq); }
        } else if (tid >= 128 && tid < 192) {
            int ch = tid - 128;
            const float4* row = (const float4*)(t + ch * PP);
            float s = 0.f;
            #pragma unroll
            for (int i = 0; i < 25; ++i) { float4 v = row[i]; s += (v.x + v.y) + (v.z + v.w); }
            if (dst_avg) dst_avg[(size_t)b * CCH + c0 + ch] = s * (1.f / PP);
        }
        if (imgb) {
            for (int i = tid; i < 3200; i += 256) {
                int cpl = i / 100, col = i - cpl * 100;
                int cp = (c0 >> 1) + cpl;
                int kt = cp >> 4, cpk = cp & 15;
                float a0 = t[(2 * cpl) * 100 + col];
                float a1 = t[(2 * cpl + 1) * 100 + col];
                uint pk = __builtin_bit_cast(uint, __builtin_amdgcn_cvt_pkrtz(a0, a1));
                imgb[(size_t)kt * 2048 + ((((cpk >> 2) << 7) | SWZ(col)) * 4 + (cpk & 3))] = pk;
            }
        }
    }
    if (tid < PP) dst_sq[b * PP + tid] = qsq;
}

// ------- K2c: fill avg row + pad slots of query images -------
__global__ __launch_bounds__(256) void k_qpad(const float* __restrict__ avg,
                                              uint* __restrict__ dst) {
    int b = blockIdx.x;
    int tid = threadIdx.x;
    uint* img = dst + (size_t)b * 32768;
    const float* av = avg + (size_t)b * CCH;
    if (tid < 256) {
        int kt = tid >> 4, cp = tid & 15;
        float a0 = av[kt * 32 + 2 * cp], a1 = av[kt * 32 + 2 * cp + 1];
        uint pk = __builtin_bit_cast(uint, __builtin_amdgcn_cvt_pkrtz(a0, a1));
        img[(size_t)kt * 2048 + (((cp >> 2) << 7) | 101) * 4 + (cp & 3)] = pk;
    }
    for (int i = tid; i < 6912; i += 256) {
        int dw = i & 3; int t2 = i >> 2;
        int k4 = t2 & 3; int t3 = t2 >> 2;
        int s_i = t3 % 27; int kt = t3 / 27;
        int s = 100 + s_i + (s_i >= 1 ? 1 : 0);   // skip slot 101
        uint val = (s == 100) ? 0x3C003C00u : 0u;
        img[(size_t)kt * 2048 + (((k4) << 7) | s) * 4 + dw] = val;
    }
}

// ------- K2b: convert f32 image -> SWZ'd f16 kt-images (protos) -------
__global__ __launch_bounds__(256) void k_conv(const float* __restrict__ src,
                                              const float* __restrict__ avg,
                                              uint* __restrict__ dst) {
    int b = blockIdx.x;          // id*16 + kt
    int id = b >> 4, kt = b & 15;
    int tid = threadIdx.x;
    int c0 = kt * 32;
    uint* img = dst + (size_t)b * 2048;
    const float* pb = src + (size_t)id * CCH * PP;
    const float* pavg = avg + (size_t)id * CCH;
    for (int i = tid; i < 1600; i += 256) {
        int cp = i / 100, col = i - cp * 100;
        float a0 = pb[(size_t)(c0 + 2 * cp) * PP + col];
        float a1 = pb[(size_t)(c0 + 2 * cp + 1) * PP + col];
        uint pk = __builtin_bit_cast(uint, __builtin_amdgcn_cvt_pkrtz(a0, a1));
        img[(((cp >> 2) << 7) | SWZ(col)) * 4 + (cp & 3)] = pk;
    }
    if (tid < 16) {
        int cp = tid;
        float a0 = pavg[c0 + 2 * cp], a1 = pavg[c0 + 2 * cp + 1];
        uint pk = __builtin_bit_cast(uint, __builtin_amdgcn_cvt_pkrtz(a0, a1));
        img[(((cp >> 2) << 7) | 101) * 4 + (cp & 3)] = pk;
    }
    for (int i = tid; i < 448; i += 256) {
        int dw = i & 3; int t2 = i >> 2;
        int s_i = t2 % 28; int k4 = t2 / 28;
        int s = 100 + s_i;
        if (s == 101) continue;
        img[(((k4) << 7) | s) * 4 + dw] = (s == 100) ? 0x3C003C00u : 0u;
    }
}

// ------- K3a-direct: 8 waves/pair, 2 col-tiles per wave -----------------
// rt = w>>1 (row-tile), ct = 2*(w&1)+tc2 (col-tile); acc=32 regs/thread
__global__ __launch_bounds__(512, 4) void k_cost2(float* __restrict__ ws) {
    __shared__ __align__(16) char SH[22400];
    __shared__ float wrL[PP], wcL[PP], qnl[PP], pnl[PP], sqv[PP], spv[PP];
    __shared__ float red[16];
    uint* Kst = (uint*)SH;

    int p_ = blockIdx.x;
    int xcd = p_ & 7, off_ = p_ >> 3;
    int pair = (xcd < 3) ? (xcd * 235 + off_) : (705 + (xcd - 3) * 234 + off_);

    int m = pair / NW;
    int n = pair - m * NW;
    int tid = threadIdx.x;
    int lane = tid & 63, w = tid >> 6;       // 8 waves
    int lrow = lane & 31, lhi = lane >> 5;
    int rt = w >> 1, cth = w & 1;

    const char* qimg = (const char*)((const uint*)(ws + OFF_QF16) + (size_t)m * 16 * 2048);
    const char* pimg = (const char*)((const uint*)(ws + OFF_PF16) + (size_t)n * 16 * 2048);

    f32x16 acc[2];
    #pragma unroll
    for (int tc = 0; tc < 2; ++tc)
        #pragma unroll
        for (int e = 0; e < 16; ++e) acc[tc][e] = 0.f;

    int arow16 = SWZ(32 * rt + lrow) * 16;
    int bcol16[2];
    #pragma unroll
    for (int tc = 0; tc < 2; ++tc) bcol16[tc] = SWZ(32 * (2 * cth + tc) + lrow) * 16;

    #pragma unroll 2
    for (int kt = 0; kt < 16; ++kt) {
        const char* qk = qimg + kt * 8192;
        const char* pk = pimg + kt * 8192;
        #pragma unroll
        for (int s = 0; s < 2; ++s) {
            int kb = (2 * s + lhi) * 2048;
            f16x8 ah = *(const f16x8*)(qk + kb + arow16);
            f16x8 b0 = *(const f16x8*)(pk + kb + bcol16[0]);
            f16x8 b1 = *(const f16x8*)(pk + kb + bcol16[1]);
            acc[0] = __builtin_amdgcn_mfma_f32_32x32x16_f16(ah, b0, acc[0], 0, 0, 0);
            acc[1] = __builtin_amdgcn_mfma_f32_32x32x16_f16(ah, b1, acc[1], 0, 0, 0);
        }
    }

    // extraction: cols 100/101 live in col-tile 3 (waves with cth==1, tc2==1)
    if (cth == 1 && ((lane & 31) == 4 || (lane & 31) == 5)) {
        float* dst = ((lane & 31) == 4) ? wrL : sqv;
        #pragma unroll
        for (int reg = 0; reg < 16; ++reg) {
            int row = 32 * rt + (reg & 3) + 8 * (reg >> 2) + 4 * lhi;
            if (row < PP) dst[row] = acc[1][reg];
        }
    }
    // rows 100/101 live in row-tile 3 (waves 6,7), reg 0/1, lhi==1
    if (rt == 3 && lhi == 1) {
        #pragma unroll
        for (int tc = 0; tc < 2; ++tc) {
            int col = 32 * (2 * cth + tc) + lrow;
            if (col < PP) { wcL[col] = acc[tc][0]; spv[col] = acc[tc][1]; }
        }
    }
    __syncthreads();

    float v1 = 0.f, v2 = 0.f;
    if (tid < PP) {
        v1 = fmaxf(wrL[tid], 0.f) + 0.00101f;
        v2 = fmaxf(wcL[tid], 0.f) + 0.00101f;
    }
    float s1 = v1, s2 = v2;
    #pragma unroll
    for (int off = 32; off; off >>= 1) { s1 += __shfl_down(s1, off); s2 += __shfl_down(s2, off); }
    if (lane == 0) { red[w] = s1; red[8 + w] = s2; }
    __syncthreads();
    float t1 = red[0] + red[1], t2 = red[8] + red[9];
    if (tid < PP) {
        wrL[tid] = v1 * (100.f / t1) * 4.f;
        wcL[tid] = v2 * (100.f / t2) * 4.f;
        float sq = sqv[tid], sp = spv[tid];
        qnl[tid] = ws[OFF_QSQ + m * PP + tid] - sq * sq * (1.f / 512.f);
        pnl[tid] = ws[OFF_PSQ + n * PP + tid] - sp * sp * (1.f / 512.f);
    }
    __syncthreads();

    float spc[2], pnc[2];
    #pragma unroll
    for (int tc = 0; tc < 2; ++tc) {
        int col = 32 * (2 * cth + tc) + lrow;
        bool cv = col < PP;
        spc[tc] = cv ? spv[col] : 0.f;
        pnc[tc] = cv ? pnl[col] : 0.f;
    }
    float mymax = -1e30f;
    #pragma unroll
    for (int reg = 0; reg < 16; ++reg) {
        int row = 32 * rt + (reg & 3) + 8 * (reg >> 2) + 4 * lhi;
        bool rv = row < PP;
        float sqr = rv ? sqv[row] : 0.f;
        float qnr = rv ? qnl[row] : 0.f;
        #pragma unroll
        for (int tc = 0; tc < 2; ++tc) {
            float sqd = qnr + pnc[tc] - 2.f * (acc[tc][reg] - sqr * spc[tc] * (1.f / 512.f));
            acc[tc][reg] = sqd;
            int col = 32 * (2 * cth + tc) + lrow;
            if (rv && col < PP) mymax = fmaxf(mymax, sqd);
        }
    }
    #pragma unroll
    for (int off = 32; off; off >>= 1) mymax = fmaxf(mymax, __shfl_down(mymax, off));
    __syncthreads();
    if (lane == 0) red[w] = mymax;
    __syncthreads();
    float scale = fmaxf(fmaxf(fmaxf(red[0], red[1]), fmaxf(red[2], red[3])),
                        fmaxf(fmaxf(red[4], red[5]), fmaxf(red[6], red[7]))) + 1e-6f;
    float k2 = (1.f / scale) * (20.f * 1.44269504088896f);

    #pragma unroll
    for (int tc = 0; tc < 2; ++tc) {
        float kv[16];
        #pragma unroll
        for (int reg = 0; reg < 16; ++reg) kv[reg] = exp2f(fmaf(-acc[tc][reg], k2, 15.f));
        int col = 32 * (2 * cth + tc) + lrow;
        #pragma unroll
        for (int reg = 0; reg < 16; ++reg) {
            float pv = __shfl_xor(kv[reg], 1);
            int row = 32 * rt + (reg & 3) + 8 * (reg >> 2) + 4 * lhi;
            if (!(lane & 1) && row < PP && col < PP) {
                int j = col >> 1;
                int dw = (j < 25) ? j : (j + 3);
                uint pk = __builtin_bit_cast(uint, __builtin_amdgcn_cvt_pkrtz(kv[reg], pv));
                Kst[row * 56 + dw] = pk;
            }
        }
    }
    __syncthreads();

    // gather rows/cols; coalesced Kg layout: K[j][row] @0, KT[rp][col] @5000
    int r_ = tid >> 1, hf = tid & 1;
    bool sact = tid < 200;
    if (sact) {
        uint Kr[25], KTr[25];
        const uint* rp = Kst + r_ * 56 + 28 * hf;
        #pragma unroll
        for (int q = 0; q < 25; ++q) Kr[q] = rp[q];
        int j = r_ >> 1;
        int dwc = (j < 25) ? j : (j + 3);
        int sh = (r_ & 1) * 16;
        const uint* cp0 = Kst + (50 * hf) * 56 + dwc;
        #pragma unroll
        for (int q = 0; q < 25; ++q) {
            uint d0 = cp0[(2 * q) * 56];
            uint d1 = cp0[(2 * q + 1) * 56];
            KTr[q] = ((d0 >> sh) & 0xFFFFu) | (((d1 >> sh) & 0xFFFFu) << 16);
        }
        uint* kg = (uint*)(ws + OFF_KG) + (size_t)pair * 10000;
        #pragma unroll
        for (int q = 0; q < 25; ++q) kg[(25 * hf + q) * 100 + r_] = Kr[q];
        #pragma unroll
        for (int q = 0; q < 25; ++q) kg[5000 + (25 * hf + q) * 100 + r_] = KTr[q];
    }
    float* aux = ws + OFF_AUX + (size_t)pair * 204;
    if (tid < PP) { aux[tid] = wrL[tid]; aux[100 + tid] = wcL[tid]; }
    if (tid == 0) aux[200] = scale;
}

// ------- K3a-fallback: LDS-staging variant (same Kg layout) -------
__global__ __launch_bounds__(256, 4) void k_costL(const float* __restrict__ query,
                                                  float* __restrict__ ws) {
    __shared__ __align__(16) char SH[22400];
    __shared__ float wrL[PP], wcL[PP], qnl[PP], pnl[PP], sqv[PP], spv[PP];
    __shared__ float red[8];
    uint* Kst = (uint*)SH;

    int p_ = blockIdx.x;
    int xcd = p_ & 7, off_ = p_ >> 3;
    int pair = (xcd < 3) ? (xcd * 235 + off_) : (705 + (xcd - 3) * 234 + off_);

    int m = pair / NW;
    int n = pair - m * NW;
    int tid = threadIdx.x;
    int lane = tid & 63, wid = tid >> 6;
    int lrow = lane & 31, lhi = lane >> 5;

    const float* qb = query + (size_t)m * CCH * PP;
    const float* qavg_g = ws + OFF_QAVG + (size_t)m * CCH;
    const uint* pimg = (const uint*)(ws + OFF_PF16) + (size_t)n * 16 * 2048;

    for (int idx = tid; idx < 112; idx += 256) {
        int s_i = idx % 28; int k4 = idx / 28;
        int s = 100 + s_i;
        if (s == 101) continue;
        uint4 val = (s == 100)
                  ? make_uint4(0x3C003C00u, 0x3C003C00u, 0x3C003C00u, 0x3C003C00u)
                  : make_uint4(0u, 0u, 0u, 0u);
        *(uint4*)&SH[(k4 * 128 + s) * 16] = val;
    }

    f32x16 acc[4];
    #pragma unroll
    for (int tc = 0; tc < 4; ++tc)
        #pragma unroll
        for (int e = 0; e < 16; ++e) acc[tc][e] = 0.f;

    int arow16 = SWZ(32 * wid + lrow) * 16;
    int bcol16[4];
    #pragma unroll
    for (int tc = 0; tc < 4; ++tc) bcol16[tc] = SWZ(32 * tc + lrow) * 16;

    for (int kt = 0; kt < 16; ++kt) {
        int c0 = kt * 32;
        for (int idx = tid; idx < 400; idx += 256) {
            int cp = idx / 25, n4 = idx - cp * 25;
            const float* src = qb + (size_t)(c0 + 2 * cp) * PP + n4 * 4;
            float4 x0 = *(const float4*)src;
            float4 x1 = *(const float4*)(src + PP);
            const float* p0 = (const float*)&x0;
            const float* p1 = (const float*)&x1;
            int basedw = ((cp >> 2) << 7);
            int dwb = (cp & 3) * 4;
            #pragma unroll
            for (int i4 = 0; i4 < 4; ++i4) {
                int node = n4 * 4 + i4;
                uint pk = __builtin_bit_cast(uint, __builtin_amdgcn_cvt_pkrtz(p0[i4], p1[i4]));
                *(uint*)&SH[(basedw + SWZ(node)) * 16 + dwb] = pk;
            }
        }
        if (tid < 16) {
            int cp = tid;
            uint pk = __builtin_bit_cast(uint,
                __builtin_amdgcn_cvt_pkrtz(qavg_g[c0 + 2 * cp], qavg_g[c0 + 2 * cp + 1]));
            *(uint*)&SH[(((cp >> 2) << 7) + 101) * 16 + (cp & 3) * 4] = pk;
        }
        {
            const float4* gB = (const float4*)(pimg + (size_t)kt * 2048);
            float4* sB = (float4*)&SH[8192];
            for (int i = tid; i < 512; i += 256) sB[i] = gB[i];
        }
        __syncthreads();
        __builtin_amdgcn_s_setprio(1);
        #pragma unroll
        for (int s = 0; s < 2; ++s) {
            int kb = (2 * s + lhi) * 2048;
            f16x8 ah = *(const f16x8*)&SH[kb + arow16];
            #pragma unroll
            for (int tc = 0; tc < 4; ++tc) {
                f16x8 bh = *(const f16x8*)&SH[8192 + kb + bcol16[tc]];
                acc[tc] = __builtin_amdgcn_mfma_f32_32x32x16_f16(ah, bh, acc[tc], 0, 0, 0);
            }
        }
        __builtin_amdgcn_s_setprio(0);
        __syncthreads();
    }

    if ((lane & 31) == 4 || (lane & 31) == 5) {
        float* dst = ((lane & 31) == 4) ? wrL : sqv;
        #pragma unroll
        for (int reg = 0; reg < 16; ++reg) {
            int row = 32 * wid + (reg & 3) + 8 * (reg >> 2) + 4 * lhi;
            if (row < PP) dst[row] = acc[3][reg];
        }
    }
    if (wid == 3 && lhi == 1) {
        #pragma unroll
        for (int tc = 0; tc < 4; ++tc) {
            int col = 32 * tc + lrow;
            if (col < PP) { wcL[col] = acc[tc][0]; spv[col] = acc[tc][1]; }
        }
    }
    __syncthreads();

    float v1 = 0.f, v2 = 0.f;
    if (tid < PP) {
        v1 = fmaxf(wrL[tid], 0.f) + 0.00101f;
        v2 = fmaxf(wcL[tid], 0.f) + 0.00101f;
    }
    float s1 = v1, s2 = v2;
    #pragma unroll
    for (int off = 32; off; off >>= 1) { s1 += __shfl_down(s1, off); s2 += __shfl_down(s2, off); }
    if ((tid & 63) == 0) { red[tid >> 6] = s1; red[4 + (tid >> 6)] = s2; }
    __syncthreads();
    float t1 = red[0] + red[1], t2 = red[4] + red[5];
    if (tid < PP) {
        wrL[tid] = v1 * (100.f / t1) * 4.f;
        wcL[tid] = v2 * (100.f / t2) * 4.f;
        float sq = sqv[tid], sp = spv[tid];
        qnl[tid] = ws[OFF_QSQ + m * PP + tid] - sq * sq * (1.f / 512.f);
        pnl[tid] = ws[OFF_PSQ + n * PP + tid] - sp * sp * (1.f / 512.f);
    }
    __syncthreads();

    float spc[4], pnc[4];
    #pragma unroll
    for (int tc = 0; tc < 4; ++tc) {
        int col = 32 * tc + lrow;
        bool cv = col < PP;
        spc[tc] = cv ? spv[col] : 0.f;
        pnc[tc] = cv ? pnl[col] : 0.f;
    }
    float mymax = -1e30f;
    #pragma unroll
    for (int reg = 0; reg < 16; ++reg) {
        int row = 32 * wid + (reg & 3) + 8 * (reg >> 2) + 4 * lhi;
        bool rv = row < PP;
        float sqr = rv ? sqv[row] : 0.f;
        float qnr = rv ? qnl[row] : 0.f;
        #pragma unroll
        for (int tc = 0; tc < 4; ++tc) {
            float sqd = qnr + pnc[tc] - 2.f * (acc[tc][reg] - sqr * spc[tc] * (1.f / 512.f));
            acc[tc][reg] = sqd;
            int col = 32 * tc + lrow;
            if (rv && col < PP) mymax = fmaxf(mymax, sqd);
        }
    }
    #pragma unroll
    for (int off = 32; off; off >>= 1) mymax = fmaxf(mymax, __shfl_down(mymax, off));
    __syncthreads();
    if (lane == 0) red[wid] = mymax;
    __syncthreads();
    float scale = fmaxf(fmaxf(red[0], red[1]), fmaxf(red[2], red[3])) + 1e-6f;
    float k2 = (1.f / scale) * (20.f * 1.44269504088896f);

    #pragma unroll
    for (int tc = 0; tc < 4; ++tc) {
        float kv[16];
        #pragma unroll
        for (int reg = 0; reg < 16; ++reg) kv[reg] = exp2f(fmaf(-acc[tc][reg], k2, 15.f));
        int col = 32 * tc + lrow;
        #pragma unroll
        for (int reg = 0; reg < 16; ++reg) {
            float pv = __shfl_xor(kv[reg], 1);
            int row = 32 * wid + (reg & 3) + 8 * (reg >> 2) + 4 * lhi;
            if (!(lane & 1) && row < PP && col < PP) {
                int j = col >> 1;
                int dw = (j < 25) ? j : (j + 3);
                uint pk = __builtin_bit_cast(uint, __builtin_amdgcn_cvt_pkrtz(kv[reg], pv));
                Kst[row * 56 + dw] = pk;
            }
        }
    }
    __syncthreads();

    int r_ = tid >> 1, hf = tid & 1;
    bool sact = tid < 200;
    if (sact) {
        uint Kr[25], KTr[25];
        const uint* rp = Kst + r_ * 56 + 28 * hf;
        #pragma unroll
        for (int q = 0; q < 25; ++q) Kr[q] = rp[q];
        int j = r_ >> 1;
        int dwc = (j < 25) ? j : (j + 3);
        int sh = (r_ & 1) * 16;
        const uint* cp0 = Kst + (50 * hf) * 56 + dwc;
        #pragma unroll
        for (int q = 0; q < 25; ++q) {
            uint d0 = cp0[(2 * q) * 56];
            uint d1 = cp0[(2 * q + 1) * 56];
            KTr[q] = ((d0 >> sh) & 0xFFFFu) | (((d1 >> sh) & 0xFFFFu) << 16);
        }
        uint* kg = (uint*)(ws + OFF_KG) + (size_t)pair * 10000;
        #pragma unroll
        for (int q = 0; q < 25; ++q) kg[(25 * hf + q) * 100 + r_] = Kr[q];
        #pragma unroll
        for (int q = 0; q < 25; ++q) kg[5000 + (25 * hf + q) * 100 + r_] = KTr[q];
    }
    float* aux = ws + OFF_AUX + (size_t)pair * 204;
    if (tid < PP) { aux[tid] = wrL[tid]; aux[100 + tid] = wcL[tid]; }
    if (tid == 0) aux[200] = scale;
}

// ------- K3b: k_sink — one wave per pair, register-resident K -------
__global__ __launch_bounds__(64, 2) void k_sink(float* __restrict__ ws) {
    __shared__ __align__(16) uint uhL[52], vhL[52];
    int pair = blockIdx.x;
    int l = threadIdx.x;
    bool act = l < 50;

    const float* aux = ws + OFF_AUX + (size_t)pair * 204;
    float wr0 = 0.f, wr1 = 0.f, wc0 = 0.f, wc1 = 0.f;
    if (act) {
        wr0 = aux[2 * l]; wr1 = aux[2 * l + 1];
        wc0 = aux[100 + 2 * l]; wc1 = aux[101 + 2 * l];
    }
    float scale = aux[200];
    float rk2 = scale * (1.f / (20.f * 1.44269504088896f));

    uint K0[50], K1[50], T0[50], T1[50];
    {
        const uint2* kg2 = (const uint2*)((const uint*)(ws + OFF_KG) + (size_t)pair * 10000);
        int ll = act ? l : 0;
        #pragma unroll
        for (int j = 0; j < 50; ++j) { uint2 kk = kg2[j * 50 + ll]; K0[j] = kk.x; K1[j] = kk.y; }
        #pragma unroll
        for (int j = 0; j < 50; ++j) { uint2 kk = kg2[2500 + j * 50 + ll]; T0[j] = kk.x; T1[j] = kk.y; }
    }
    if (l < 52) { vhL[l] = (l < 50) ? 0x3C003C00u : 0u; uhL[l] = 0u; }
    __syncthreads();

    float u0 = 0.f, u1 = 0.f;
    for (int it = 0; it < 50; ++it) {
        if (act) {
            const uint4* vp4 = (const uint4*)vhL;
            float a0 = 0.f, b0 = 0.f, a1 = 0.f, b1 = 0.f;
            #pragma unroll
            for (int d4 = 0; d4 < 12; ++d4) {
                uint4 V = vp4[d4];
                a0 = __builtin_amdgcn_fdot2(__builtin_bit_cast(f16x2, K0[4*d4+0]), __builtin_bit_cast(f16x2, V.x), a0, false);
                b0 = __builtin_amdgcn_fdot2(__builtin_bit_cast(f16x2, K0[4*d4+1]), __builtin_bit_cast(f16x2, V.y), b0, false);
                a0 = __builtin_amdgcn_fdot2(__builtin_bit_cast(f16x2, K0[4*d4+2]), __builtin_bit_cast(f16x2, V.z), a0, false);
                b0 = __builtin_amdgcn_fdot2(__builtin_bit_cast(f16x2, K0[4*d4+3]), __builtin_bit_cast(f16x2, V.w), b0, false);
                a1 = __builtin_amdgcn_fdot2(__builtin_bit_cast(f16x2, K1[4*d4+0]), __builtin_bit_cast(f16x2, V.x), a1, false);
                b1 = __builtin_amdgcn_fdot2(__builtin_bit_cast(f16x2, K1[4*d4+1]), __builtin_bit_cast(f16x2, V.y), b1, false);
                a1 = __builtin_amdgcn_fdot2(__builtin_bit_cast(f16x2, K1[4*d4+2]), __builtin_bit_cast(f16x2, V.z), a1, false);
                b1 = __builtin_amdgcn_fdot2(__builtin_bit_cast(f16x2, K1[4*d4+3]), __builtin_bit_cast(f16x2, V.w), b1, false);
            }
            {
                uint v48 = vhL[48], v49 = vhL[49];
                a0 = __builtin_amdgcn_fdot2(__builtin_bit_cast(f16x2, K0[48]), __builtin_bit_cast(f16x2, v48), a0, false);
                b0 = __builtin_amdgcn_fdot2(__builtin_bit_cast(f16x2, K0[49]), __builtin_bit_cast(f16x2, v49), b0, false);
                a1 = __builtin_amdgcn_fdot2(__builtin_bit_cast(f16x2, K1[48]), __builtin_bit_cast(f16x2, v48), a1, false);
                b1 = __builtin_amdgcn_fdot2(__builtin_bit_cast(f16x2, K1[49]), __builtin_bit_cast(f16x2, v49), b1, false);
            }
            u0 = fminf(wr0 * __builtin_amdgcn_rcpf(a0 + b0), 60000.f);
            u1 = fminf(wr1 * __builtin_amdgcn_rcpf(a1 + b1), 60000.f);
            uhL[l] = __builtin_bit_cast(uint, __builtin_amdgcn_cvt_pkrtz(u0, u1));
        }
        __syncthreads();
        if (act) {
            const uint4* up4 = (const uint4*)uhL;
            float a0 = 0.f, b0 = 0.f, a1 = 0.f, b1 = 0.f;
            #pragma unroll
            for (int d4 = 0; d4 < 12; ++d4) {
                uint4 U = up4[d4];
                a0 = __builtin_amdgcn_fdot2(__builtin_bit_cast(f16x2, T0[4*d4+0]), __builtin_bit_cast(f16x2, U.x), a0, false);
                b0 = __builtin_amdgcn_fdot2(__builtin_bit_cast(f16x2, T0[4*d4+1]), __builtin_bit_cast(f16x2, U.y), b0, false);
                a0 = __builtin_amdgcn_fdot2(__builtin_bit_cast(f16x2, T0[4*d4+2]), __builtin_bit_cast(f16x2, U.z), a0, false);
                b0 = __builtin_amdgcn_fdot2(__builtin_bit_cast(f16x2, T0[4*d4+3]), __builtin_bit_cast(f16x2, U.w), b0, false);
                a1 = __builtin_amdgcn_fdot2(__builtin_bit_cast(f16x2, T1[4*d4+0]), __builtin_bit_cast(f16x2, U.x), a1, false);
                b1 = __builtin_amdgcn_fdot2(__builtin_bit_cast(f16x2, T1[4*d4+1]), __builtin_bit_cast(f16x2, U.y), b1, false);
                a1 = __builtin_amdgcn_fdot2(__builtin_bit_cast(f16x2, T1[4*d4+2]), __builtin_bit_cast(f16x2, U.z), a1, false);
                b1 = __builtin_amdgcn_fdot2(__builtin_bit_cast(f16x2, T1[4*d4+3]), __builtin_bit_cast(f16x2, U.w), b1, false);
            }
            {
                uint u48 = uhL[48], u49 = uhL[49];
                a0 = __builtin_amdgcn_fdot2(__builtin_bit_cast(f16x2, T0[48]), __builtin_bit_cast(f16x2, u48), a0, false);
                b0 = __builtin_amdgcn_fdot2(__builtin_bit_cast(f16x2, T0[49]), __builtin_bit_cast(f16x2, u49), b0, false);
                a1 = __builtin_amdgcn_fdot2(__builtin_bit_cast(f16x2, T1[48]), __builtin_bit_cast(f16x2, u48), a1, false);
                b1 = __builtin_amdgcn_fdot2(__builtin_bit_cast(f16x2, T1[49]), __builtin_bit_cast(f16x2, u49), b1, false);
            }
            float v0 = fminf(wc0 * __builtin_amdgcn_rcpf(a0 + b0), 60000.f);
            float v1n = fminf(wc1 * __builtin_amdgcn_rcpf(a1 + b1), 60000.f);
            vhL[l] = __builtin_bit_cast(uint, __builtin_amdgcn_cvt_pkrtz(v0, v1n));
        }
        __syncthreads();
    }

    float lsum = 0.f;
    if (act) {
        float l0 = 0.f, l1 = 0.f;
        #pragma unroll
        for (int d = 0; d < 50; ++d) {
            f16x2 vv = __builtin_bit_cast(f16x2, vhL[d]);
            f16x2 h0 = __builtin_bit_cast(f16x2, K0[d]);
            f16x2 h1 = __builtin_bit_cast(f16x2, K1[d]);
            float k00 = (float)h0[0], k01 = (float)h0[1];
            float k10 = (float)h1[0], k11 = (float)h1[1];
            float v0 = (float)vv[0], v1v = (float)vv[1];
            l0 = fmaf((1.f - (15.f - __log2f(k00)) * rk2) * k00, v0, l0);
            l0 = fmaf((1.f - (15.f - __log2f(k01)) * rk2) * k01, v1v, l0);
            l1 = fmaf((1.f - (15.f - __log2f(k10)) * rk2) * k10, v0, l1);
            l1 = fmaf((1.f - (15.f - __log2f(k11)) * rk2) * k11, v1v, l1);
        }
        lsum = l0 * u0 + l1 * u1;
    }
    #pragma unroll
    for (int off = 32; off; off >>= 1) lsum += __shfl_down(lsum, off);
    if (l == 0) ws[OFF_LOGITS + pair] = lsum * (0.125f / 4.f);
}

// ---------------- K4: log-softmax + loss --------------------------------
__global__ void k_final(const int* __restrict__ label, const float* __restrict__ ws,
                        float* __restrict__ out) {
    int t = threadIdx.x;
    float contrib = 0.f;
    if (t < NQ) {
        float lg[NW];
        #pragma unroll
        for (int n = 0; n < NW; ++n) lg[n] = ws[OFF_LOGITS + t * NW + n];
        float mx = lg[0];
        #pragma unroll
        for (int n = 1; n < NW; ++n) mx = fmaxf(mx, lg[n]);
        float s = 0.f;
        #pragma unroll
        for (int n = 0; n < NW; ++n) s += expf(lg[n] - mx);
        float lse = mx + logf(s);
        int lab = label[t];
        #pragma unroll
        for (int n = 0; n < NW; ++n) {
            float lp = lg[n] - lse;
            out[t * NW + n] = lp;
            if (n == lab) contrib = -lp;
        }
    }
    #pragma unroll
    for (int off = 32; off; off >>= 1) contrib += __shfl_down(contrib, off);
    __shared__ float red[6];
    if ((t & 63) == 0) red[t >> 6] = contrib;
    __syncthreads();
    if (t == 0) {
        float s = 0.f;
        #pragma unroll
        for (int i = 0; i < 6; ++i) s += red[i];
        out[NQ * NW] = s * (1.f / NQ);
    }
}

extern "C" void kernel_launch(void* const* d_in, const int* in_sizes, int n_in,
                              void* d_out, int out_size, void* d_ws, size_t ws_size,
                              hipStream_t stream) {
    const float* feat  = (const float*)d_in[0];
    const int*   label = (const int*)d_in[1];
    float* out = (float*)d_out;
    float* ws  = (float*)d_ws;
    const float* query = feat + (size_t)NS * CCH * PP;
    bool fast = ws_size >= REQ2_WS_BYTES;

    k_proto<<<NW * CCH, 128, 0, stream>>>(feat, ws);
    k_qstat<<<NQ, 256, 0, stream>>>(query, ws + OFF_QSQ, ws + OFF_QAVG,
                                    fast ? (uint*)(ws + OFF_QF16) : (uint*)0);
    k_qstat<<<NW, 256, 0, stream>>>(ws + OFF_PROTO, ws + OFF_PSQ, (float*)0, (uint*)0);
    k_conv<<<NW * 16, 256, 0, stream>>>(ws + OFF_PROTO, ws + OFF_PAVG, (uint*)(ws + OFF_PF16));
    if (fast) {
        k_qpad<<<NQ, 256, 0, stream>>>(ws + OFF_QAVG, (uint*)(ws + OFF_QF16));
        k_cost2<<<NPAIR, 512, 0, stream>>>(ws);
        k_sink<<<NPAIR, 64, 0, stream>>>(ws);
    } else {
        k_costL<<<NPAIR, 256, 0, stream>>>(query, ws);
        k_sink<<<NPAIR, 64, 0, stream>>>(ws);
    }
    k_final<<<1, 384, 0, stream>>>(label, ws, out);
}